// Round 6
// baseline (1095.897 us; speedup 1.0000x reference)
//
#include <hip/hip_runtime.h>

#define T_TOK 8192
#define HDIM  2048
#define NEXP  32
#define IDIM  1024

#define BM 128
#define BN 128
#define BK 64
#define CAP (T_TOK*2 + NEXP*BM)   // 20480 max padded rows
#define MAX_RT (CAP/BM)           // 160 row tiles max
#define G1B (MAX_RT*8)            // 1280 gemm1 blocks
#define TRB (NEXP*512)            // 16384 transpose blocks per matrix
#define CVB 8192                  // cvt_hs blocks

typedef __attribute__((ext_vector_type(8))) short bh8;   // 8 bf16 (4 VGPR) MFMA A/B frag
typedef __attribute__((ext_vector_type(4))) float f4;    // MFMA C/D frag

// fp32 -> bf16 round-to-nearest-even (bit pattern)
__device__ __forceinline__ unsigned short f2bf(float f) {
    unsigned u = __builtin_bit_cast(unsigned, f);
    u += 0x7FFFu + ((u >> 16) & 1u);
    return (unsigned short)(u >> 16);
}

// XOR swizzle: 128-byte LDS rows, byte ^= (row&7)<<4.  (proven 0-conflict, rounds 1-2)
__device__ __forceinline__ int swz(int row, int kb) {
    return row * 128 + (kb ^ ((row & 7) << 4));
}

// async 16B global->LDS (dest = wave-uniform base + lane*16, source per-lane)
__device__ __forceinline__ void gload16(const void* g, void* l) {
    __builtin_amdgcn_global_load_lds(
        (const __attribute__((address_space(1))) unsigned int*)g,
        (__attribute__((address_space(3))) unsigned int*)l,
        16, 0, 0);
}

// ---------------- routing ----------------

__device__ __forceinline__ void top2(const float* __restrict__ l,
                                     int& b1, float& v1, int& b2, float& v2) {
    v1 = -1e30f; b1 = 0;
#pragma unroll
    for (int e = 0; e < NEXP; ++e) { float v = l[e]; if (v > v1) { v1 = v; b1 = e; } }
    v2 = -1e30f; b2 = 0;
#pragma unroll
    for (int e = 0; e < NEXP; ++e) { if (e == b1) continue; float v = l[e]; if (v > v2) { v2 = v; b2 = e; } }
}

__global__ void route_count_kernel(const float* __restrict__ logits, int* __restrict__ counts) {
    int t = blockIdx.x * blockDim.x + threadIdx.x;
    if (t >= T_TOK) return;
    int b1, b2; float v1, v2;
    top2(logits + (size_t)t * NEXP, b1, v1, b2, v2);
    atomicAdd(&counts[b1], 1);
    atomicAdd(&counts[b2], 1);
}

__global__ void offsets_kernel(const int* __restrict__ counts, int* __restrict__ offs) {
    if (threadIdx.x == 0) {
        int o = 0;
        for (int e = 0; e < NEXP; ++e) { offs[e] = o; o += (counts[e] + BM - 1) & ~(BM - 1); }
        offs[NEXP] = o;
    }
}

__global__ void route_scatter_kernel(const float* __restrict__ logits,
                                     const float* __restrict__ scale,
                                     const int* __restrict__ offs,
                                     int* __restrict__ cursor,
                                     int* __restrict__ row_tok,
                                     float* __restrict__ row_w) {
    int t = blockIdx.x * blockDim.x + threadIdx.x;
    if (t >= T_TOK) return;
    int b1, b2; float v1, v2;
    top2(logits + (size_t)t * NEXP, b1, v1, b2, v2);
    float e2 = expf(v2 - v1);
    float inv = 1.0f / (1.0f + e2);
    float w1 = scale[b1] * inv;
    float w2 = scale[b2] * e2 * inv;
    int p1 = offs[b1] + atomicAdd(&cursor[b1], 1);
    row_tok[p1] = t; row_w[p1] = w1;
    int p2 = offs[b2] + atomicAdd(&cursor[b2], 1);
    row_tok[p2] = t; row_w[p2] = w2;
}

// ---------------- prep: convert + transpose (round-2 proven bodies) ----------------

// [E][K][N] fp32 -> [E][N][K] bf16, 64x64 tiles, register-only transpose.
__device__ __forceinline__ void transpose_cvt_dev(const float* __restrict__ in,
                                                  unsigned short* __restrict__ out,
                                                  int K, int N, int tilesN, int bid) {
    int e = bid >> 9;            // 512 tiles per expert for both shapes
    int tile = bid & 511;
    int k0 = (tile / tilesN) * 64;
    int n0 = (tile % tilesN) * 64;
    const float* src = in + (size_t)e * K * N;
    unsigned short* dst = out + (size_t)e * K * N;
    int tid = threadIdx.x, l = tid & 63, w = tid >> 6;
    int n = n0 + w * 16 + (l >> 2);
#pragma unroll
    for (int p = 0; p < 2; ++p) {
        int kc = k0 + p * 32 + (l & 3) * 8;
        const float* s = src + (size_t)kc * N + n;
        bh8 v;
#pragma unroll
        for (int j = 0; j < 8; ++j) v[j] = (short)f2bf(s[(size_t)j * N]);
        *(bh8*)(dst + (size_t)n * K + kc) = v;
    }
}

// Fused: cvt_hs | wg transpose | wu transpose — one launch, fully parallel.
__global__ void prep_all(const float* __restrict__ hs, unsigned short* __restrict__ hsb,
                         const float* __restrict__ wg, unsigned short* __restrict__ wgT,
                         const float* __restrict__ wu, unsigned short* __restrict__ wuT) {
    int b = blockIdx.x;
    if (b < CVB) {
        size_t i = ((size_t)b * 256 + threadIdx.x) * 8;
        float4 a = *(const float4*)(hs + i);
        float4 c = *(const float4*)(hs + i + 4);
        bh8 v;
        v[0] = (short)f2bf(a.x); v[1] = (short)f2bf(a.y);
        v[2] = (short)f2bf(a.z); v[3] = (short)f2bf(a.w);
        v[4] = (short)f2bf(c.x); v[5] = (short)f2bf(c.y);
        v[6] = (short)f2bf(c.z); v[7] = (short)f2bf(c.w);
        *(bh8*)(hsb + i) = v;
    } else if (b < CVB + TRB) {
        transpose_cvt_dev(wg, wgT, HDIM, IDIM, 16, b - CVB);
    } else {
        transpose_cvt_dev(wu, wuT, HDIM, IDIM, 16, b - CVB - TRB);
    }
}

// standalone wd transpose (serial fallback path)
__global__ void transpose_wd_kernel(const float* __restrict__ wd, unsigned short* __restrict__ wdT) {
    transpose_cvt_dev(wd, wdT, IDIM, HDIM, 32, blockIdx.x);
}

// ============ GEMM1 (+ optional fat wd-transpose blocks) ============
// Round-2 proven body: 128 rows x 128 cols(G)+128(U), waves 2x2 (64x64 each).
// All operands bf16 via gload16, pre-swizzled sources, zero-conflict LDS.
__launch_bounds__(256, 3)
__global__ void gemm1n_kernel(const unsigned short* __restrict__ hsb,
                              const unsigned short* __restrict__ wgT,
                              const unsigned short* __restrict__ wuT,
                              const int* __restrict__ offs,
                              const int* __restrict__ row_tok,
                              unsigned short* __restrict__ act,
                              const float* __restrict__ wd,
                              unsigned short* __restrict__ wdT) {
    if (blockIdx.x >= G1B) {   // fat section: wd transpose, concurrent with gemm1
        transpose_cvt_dev(wd, wdT, IDIM, HDIM, 32, blockIdx.x - G1B);
        return;
    }
    __shared__ char lds[49152];
    char* Xb = lds;
    char* Gb = lds + 16384;
    char* Ub = lds + 32768;

    int rt = blockIdx.x >> 3;
    int nt = blockIdx.x & 7;
    int total = offs[NEXP];
    if (rt * BM >= total) return;
    int e = 0;
    while (offs[e + 1] <= rt * BM) e++;

    int tid = threadIdx.x, l = tid & 63, wv = tid >> 6;
    int wm = wv >> 1, wn = wv & 1;

    // per-lane pre-swizzled source chunk within a 128B row
    unsigned srcChunk = ((l & 7) * 16) ^ ((l >> 3) << 4);

    unsigned xoff[4], goff[4];
#pragma unroll
    for (int i = 0; i < 4; ++i) {
        int r = i * 32 + wv * 8 + (l >> 3);
        int tok = row_tok[rt * BM + r];
        if (tok < 0) tok = 0;
        xoff[i] = (unsigned)tok * (HDIM * 2) + srcChunk;
        unsigned wrow = (unsigned)e * IDIM + nt * BN + r;
        goff[i] = wrow * (HDIM * 2) + srcChunk;
    }

    f4 accG[4][4], accU[4][4];
#pragma unroll
    for (int mi = 0; mi < 4; ++mi)
#pragma unroll
        for (int ni = 0; ni < 4; ++ni) { accG[mi][ni] = (f4)0.0f; accU[mi][ni] = (f4)0.0f; }

    const char* hsc = (const char*)hsb;
    const char* wgc = (const char*)wgT;
    const char* wuc = (const char*)wuT;

    for (int kt = 0; kt < HDIM / BK; ++kt) {
        unsigned kby = kt * 128;
#pragma unroll
        for (int i = 0; i < 4; ++i)
            gload16(hsc + (size_t)xoff[i] + kby, Xb + i * 4096 + wv * 1024);
#pragma unroll
        for (int i = 0; i < 4; ++i)
            gload16(wgc + (size_t)goff[i] + kby, Gb + i * 4096 + wv * 1024);
#pragma unroll
        for (int i = 0; i < 4; ++i)
            gload16(wuc + (size_t)goff[i] + kby, Ub + i * 4096 + wv * 1024);
        __syncthreads();

#pragma unroll
        for (int ks = 0; ks < 2; ++ks) {
            int kb = ks * 64 + ((l >> 4) << 4);
            bh8 a[4], g[4], u[4];
#pragma unroll
            for (int mi = 0; mi < 4; ++mi)
                a[mi] = *(const bh8*)(Xb + swz(wm * 64 + mi * 16 + (l & 15), kb));
#pragma unroll
            for (int ni = 0; ni < 4; ++ni) {
                int nr = wn * 64 + ni * 16 + (l & 15);
                g[ni] = *(const bh8*)(Gb + swz(nr, kb));
                u[ni] = *(const bh8*)(Ub + swz(nr, kb));
            }
#pragma unroll
            for (int mi = 0; mi < 4; ++mi)
#pragma unroll
                for (int ni = 0; ni < 4; ++ni) {
                    accG[mi][ni] = __builtin_amdgcn_mfma_f32_16x16x32_bf16(a[mi], g[ni], accG[mi][ni], 0, 0, 0);
                    accU[mi][ni] = __builtin_amdgcn_mfma_f32_16x16x32_bf16(a[mi], u[ni], accU[mi][ni], 0, 0, 0);
                }
        }
        __syncthreads();
    }

    // epilogue: gelu(g)*u -> bf16 act, pre-swizzled byte layout
    char* actc = (char*)act;
#pragma unroll
    for (int mi = 0; mi < 4; ++mi) {
#pragma unroll
        for (int i = 0; i < 4; ++i) {
            int r = rt * BM + wm * 64 + mi * 16 + ((l >> 4) << 2) + i;
            size_t rowbase = (size_t)r * (IDIM * 2);
            int rs = (r & 7) << 4;
#pragma unroll
            for (int ni = 0; ni < 4; ++ni) {
                int col = nt * BN + wn * 64 + ni * 16 + (l & 15);
                float gv = accG[mi][ni][i], uv = accU[mi][ni][i];
                float gl = 0.5f * gv * (1.0f + erff(gv * 0.70710678118654752f));
                *(unsigned short*)(actc + rowbase + ((col * 2) ^ rs)) = f2bf(gl * uv);
            }
        }
    }
}

// ============ GEMM2: out[tok] += w * (act @ WdT^T) ============
// Round-2 proven body: 128 rows x 256 cols, waves 2x2 (64x128).
__launch_bounds__(256, 2)
__global__ void gemm2n_kernel(const unsigned short* __restrict__ act,
                              const unsigned short* __restrict__ wdT,
                              const int* __restrict__ offs,
                              const int* __restrict__ row_tok,
                              const float* __restrict__ row_w,
                              float* __restrict__ out) {
    __shared__ char lds[49152];
    char* Xb = lds;          // 128 x 128B
    char* Db = lds + 16384;  // 256 x 128B

    int rt = blockIdx.x >> 3;
    int nt = blockIdx.x & 7;   // 2048 / 256
    int total = offs[NEXP];
    if (rt * BM >= total) return;
    int e = 0;
    while (offs[e + 1] <= rt * BM) e++;

    int tid = threadIdx.x, l = tid & 63, wv = tid >> 6;
    int wm = wv >> 1, wn = wv & 1;

    unsigned srcChunk = ((l & 7) * 16) ^ ((l >> 3) << 4);

    unsigned aoff[4];
#pragma unroll
    for (int i = 0; i < 4; ++i) {
        int r = i * 32 + wv * 8 + (l >> 3);
        aoff[i] = (unsigned)(rt * BM + r) * (IDIM * 2) + (l & 7) * 16;  // act pre-swizzled: linear source
    }
    unsigned doff[8];
#pragma unroll
    for (int i = 0; i < 8; ++i) {
        int r = i * 32 + wv * 8 + (l >> 3);
        doff[i] = ((unsigned)e * HDIM + nt * 256 + r) * (IDIM * 2) + srcChunk;
    }

    f4 acc[4][8];
#pragma unroll
    for (int mi = 0; mi < 4; ++mi)
#pragma unroll
        for (int ni = 0; ni < 8; ++ni) acc[mi][ni] = (f4)0.0f;

    const char* actc = (const char*)act;
    const char* wdc = (const char*)wdT;

    for (int kt = 0; kt < IDIM / BK; ++kt) {
        unsigned kby = kt * 128;
#pragma unroll
        for (int i = 0; i < 4; ++i)
            gload16(actc + (size_t)aoff[i] + kby, Xb + i * 4096 + wv * 1024);
#pragma unroll
        for (int i = 0; i < 8; ++i)
            gload16(wdc + (size_t)doff[i] + kby, Db + i * 4096 + wv * 1024);
        __syncthreads();

#pragma unroll
        for (int ks = 0; ks < 2; ++ks) {
            int kb = ks * 64 + ((l >> 4) << 4);
            bh8 a[4], b[8];
#pragma unroll
            for (int mi = 0; mi < 4; ++mi)
                a[mi] = *(const bh8*)(Xb + swz(wm * 64 + mi * 16 + (l & 15), kb));
#pragma unroll
            for (int ni = 0; ni < 8; ++ni)
                b[ni] = *(const bh8*)(Db + swz(wn * 128 + ni * 16 + (l & 15), kb));
#pragma unroll
            for (int mi = 0; mi < 4; ++mi)
#pragma unroll
                for (int ni = 0; ni < 8; ++ni)
                    acc[mi][ni] = __builtin_amdgcn_mfma_f32_16x16x32_bf16(a[mi], b[ni], acc[mi][ni], 0, 0, 0);
        }
        __syncthreads();
    }

    // epilogue: scale by routing weight, atomic accumulate
#pragma unroll
    for (int mi = 0; mi < 4; ++mi) {
#pragma unroll
        for (int i = 0; i < 4; ++i) {
            int r = rt * BM + wm * 64 + mi * 16 + ((l >> 4) << 2) + i;
            int tok = row_tok[r];
            if (tok < 0) continue;
            float w = row_w[r];
            float* op = out + (size_t)tok * HDIM + nt * 256 + wn * 128 + (l & 15);
#pragma unroll
            for (int ni = 0; ni < 8; ++ni)
                atomicAdd(op + ni * 16, acc[mi][ni][i] * w);
        }
    }
}

// ---------------- launch ----------------
// ws layout:
//   [0,512): counts(128) | cursor(128) | offs(132)
//   512:            row_tok  CAP*4
//   512+CAP*4:      row_w    CAP*4
//   164352:         act      CAP*IDIM*2     (41.9 MB)
//   +actB:          hs_bf16  T*H*2          (33.6 MB)
//   +hsB:           wgT      E*I*H*2        (134.2 MB)
//   +wTB:           wuT      E*I*H*2        (134.2 MB)   -> needSerial = 344.1 MB
//   +wTB:           wdT      E*I*H*2        (134.2 MB)   -> needFat    = 478.3 MB
// Serial path (ws < needFat): wdT reuses wgT after gemm1 (round-2 proven).

extern "C" void kernel_launch(void* const* d_in, const int* in_sizes, int n_in,
                              void* d_out, int out_size, void* d_ws, size_t ws_size,
                              hipStream_t stream) {
    const float* hs     = (const float*)d_in[0];
    const float* logits = (const float*)d_in[1];
    const float* scale  = (const float*)d_in[2];
    const float* wg     = (const float*)d_in[3];
    const float* wu     = (const float*)d_in[4];
    const float* wd     = (const float*)d_in[5];
    float* out = (float*)d_out;

    char* ws = (char*)d_ws;
    int*   counts  = (int*)ws;
    int*   cursor  = counts + 32;
    int*   offs    = cursor + 32;
    int*   row_tok = (int*)(ws + 512);
    float* row_w   = (float*)(ws + 512 + (size_t)CAP * 4);

    size_t base = 512 + (size_t)CAP * 8;
    size_t actB = (size_t)CAP * IDIM * 2;
    size_t hsB  = (size_t)T_TOK * HDIM * 2;
    size_t wTB  = (size_t)NEXP * IDIM * HDIM * 2;

    unsigned short* act = (unsigned short*)(ws + base);
    unsigned short* hsb = (unsigned short*)(ws + base + actB);
    unsigned short* wgT = (unsigned short*)(ws + base + actB + hsB);
    unsigned short* wuT = (unsigned short*)(ws + base + actB + hsB + wTB);
    unsigned short* wdT = (unsigned short*)(ws + base + actB + hsB + 2 * wTB);

    size_t needFat = base + actB + hsB + 3 * wTB;
    bool fat = (ws_size >= needFat);

    hipMemsetAsync(counts, 0, 512, stream);
    hipMemsetAsync(row_tok, 0xFF, (size_t)CAP * 4, stream);
    hipMemsetAsync(out, 0, (size_t)out_size * sizeof(float), stream);

    route_count_kernel<<<T_TOK / 256, 256, 0, stream>>>(logits, counts);
    offsets_kernel<<<1, 64, 0, stream>>>(counts, offs);
    route_scatter_kernel<<<T_TOK / 256, 256, 0, stream>>>(logits, scale, offs, cursor, row_tok, row_w);

    prep_all<<<CVB + 2 * TRB, 256, 0, stream>>>(hs, hsb, wg, wgT, wu, wuT);

    if (fat) {
        // gemm1 blocks + wd-transpose blocks co-scheduled in one launch
        gemm1n_kernel<<<G1B + TRB, 256, 0, stream>>>(hsb, wgT, wuT, offs, row_tok, act, wd, wdT);
        gemm2n_kernel<<<MAX_RT * 8, 256, 0, stream>>>(act, wdT, offs, row_tok, row_w, out);
    } else {
        gemm1n_kernel<<<G1B, 256, 0, stream>>>(hsb, wgT, wuT, offs, row_tok, act, wd, wgT /*unused*/);
        transpose_wd_kernel<<<TRB, 256, 0, stream>>>(wd, wgT);   // reuse wgT region
        gemm2n_kernel<<<MAX_RT * 8, 256, 0, stream>>>(act, wgT, offs, row_tok, row_w, out);
    }
}

// Round 7
// 798.772 us; speedup vs baseline: 1.3720x; 1.3720x over previous
//
#include <hip/hip_runtime.h>

#define T_TOK 8192
#define HDIM  2048
#define NEXP  32
#define IDIM  1024

#define BM 128
#define BN 128
#define BK 64
#define CAP (T_TOK*2 + NEXP*BM)   // 20480 max padded rows
#define MAX_RT (CAP/BM)           // 160 row tiles max
#define G1B (MAX_RT*8)            // 1280 gemm1 blocks
#define TRB (NEXP*512)            // 16384 transpose tiles per matrix
#define CVB 8192                  // cvt_hs blocks
#define FATB 256                  // grid-strided wd-transpose blocks inside gemm1
#define G1GRID (G1B + FATB)       // 1536 = 6*256: 1-in-6 interleave

typedef __attribute__((ext_vector_type(8))) short bh8;   // 8 bf16 (4 VGPR) MFMA A/B frag
typedef __attribute__((ext_vector_type(4))) float f4;    // MFMA C/D frag

// fp32 -> bf16 round-to-nearest-even (bit pattern)
__device__ __forceinline__ unsigned short f2bf(float f) {
    unsigned u = __builtin_bit_cast(unsigned, f);
    u += 0x7FFFu + ((u >> 16) & 1u);
    return (unsigned short)(u >> 16);
}

// XOR swizzle: 128-byte LDS rows, byte ^= (row&7)<<4.  (proven 0-conflict, rounds 1-2)
__device__ __forceinline__ int swz(int row, int kb) {
    return row * 128 + (kb ^ ((row & 7) << 4));
}

// async 16B global->LDS (dest = wave-uniform base + lane*16, source per-lane)
__device__ __forceinline__ void gload16(const void* g, void* l) {
    __builtin_amdgcn_global_load_lds(
        (const __attribute__((address_space(1))) unsigned int*)g,
        (__attribute__((address_space(3))) unsigned int*)l,
        16, 0, 0);
}

// ---------------- routing ----------------

__device__ __forceinline__ void top2(const float* __restrict__ l,
                                     int& b1, float& v1, int& b2, float& v2) {
    v1 = -1e30f; b1 = 0;
#pragma unroll
    for (int e = 0; e < NEXP; ++e) { float v = l[e]; if (v > v1) { v1 = v; b1 = e; } }
    v2 = -1e30f; b2 = 0;
#pragma unroll
    for (int e = 0; e < NEXP; ++e) { if (e == b1) continue; float v = l[e]; if (v > v2) { v2 = v; b2 = e; } }
}

__global__ void route_count_kernel(const float* __restrict__ logits, int* __restrict__ counts) {
    int t = blockIdx.x * blockDim.x + threadIdx.x;
    if (t >= T_TOK) return;
    int b1, b2; float v1, v2;
    top2(logits + (size_t)t * NEXP, b1, v1, b2, v2);
    atomicAdd(&counts[b1], 1);
    atomicAdd(&counts[b2], 1);
}

__global__ void offsets_kernel(const int* __restrict__ counts, int* __restrict__ offs) {
    if (threadIdx.x == 0) {
        int o = 0;
        for (int e = 0; e < NEXP; ++e) { offs[e] = o; o += (counts[e] + BM - 1) & ~(BM - 1); }
        offs[NEXP] = o;
    }
}

__global__ void route_scatter_kernel(const float* __restrict__ logits,
                                     const float* __restrict__ scale,
                                     const int* __restrict__ offs,
                                     int* __restrict__ cursor,
                                     int* __restrict__ row_tok,
                                     float* __restrict__ row_w) {
    int t = blockIdx.x * blockDim.x + threadIdx.x;
    if (t >= T_TOK) return;
    int b1, b2; float v1, v2;
    top2(logits + (size_t)t * NEXP, b1, v1, b2, v2);
    float e2 = expf(v2 - v1);
    float inv = 1.0f / (1.0f + e2);
    float w1 = scale[b1] * inv;
    float w2 = scale[b2] * e2 * inv;
    int p1 = offs[b1] + atomicAdd(&cursor[b1], 1);
    row_tok[p1] = t; row_w[p1] = w1;
    int p2 = offs[b2] + atomicAdd(&cursor[b2], 1);
    row_tok[p2] = t; row_w[p2] = w2;
}

// ---------------- prep: convert + transpose ----------------

// [E][K][N] fp32 -> [E][N][K] bf16, 64x64 tiles, register-only transpose.
__device__ __forceinline__ void transpose_cvt_dev(const float* __restrict__ in,
                                                  unsigned short* __restrict__ out,
                                                  int K, int N, int tilesN, int bid) {
    int e = bid >> 9;            // 512 tiles per expert for both shapes
    int tile = bid & 511;
    int k0 = (tile / tilesN) * 64;
    int n0 = (tile % tilesN) * 64;
    const float* src = in + (size_t)e * K * N;
    unsigned short* dst = out + (size_t)e * K * N;
    int tid = threadIdx.x, l = tid & 63, w = tid >> 6;
    int n = n0 + w * 16 + (l >> 2);
#pragma unroll
    for (int p = 0; p < 2; ++p) {
        int kc = k0 + p * 32 + (l & 3) * 8;
        const float* s = src + (size_t)kc * N + n;
        bh8 v;
#pragma unroll
        for (int j = 0; j < 8; ++j) v[j] = (short)f2bf(s[(size_t)j * N]);
        *(bh8*)(dst + (size_t)n * K + kc) = v;
    }
}

// Fused: cvt_hs | wg transpose | wu transpose — one launch, fully parallel.
__global__ void prep_all(const float* __restrict__ hs, unsigned short* __restrict__ hsb,
                         const float* __restrict__ wg, unsigned short* __restrict__ wgT,
                         const float* __restrict__ wu, unsigned short* __restrict__ wuT) {
    int b = blockIdx.x;
    if (b < CVB) {
        size_t i = ((size_t)b * 256 + threadIdx.x) * 8;
        float4 a = *(const float4*)(hs + i);
        float4 c = *(const float4*)(hs + i + 4);
        bh8 v;
        v[0] = (short)f2bf(a.x); v[1] = (short)f2bf(a.y);
        v[2] = (short)f2bf(a.z); v[3] = (short)f2bf(a.w);
        v[4] = (short)f2bf(c.x); v[5] = (short)f2bf(c.y);
        v[6] = (short)f2bf(c.z); v[7] = (short)f2bf(c.w);
        *(bh8*)(hsb + i) = v;
    } else if (b < CVB + TRB) {
        transpose_cvt_dev(wg, wgT, HDIM, IDIM, 16, b - CVB);
    } else {
        transpose_cvt_dev(wu, wuT, HDIM, IDIM, 16, b - CVB - TRB);
    }
}

// standalone wd transpose (serial fallback path)
__global__ void transpose_wd_kernel(const float* __restrict__ wd, unsigned short* __restrict__ wdT) {
    transpose_cvt_dev(wd, wdT, IDIM, HDIM, 32, blockIdx.x);
}

// ============ GEMM1 (2-phase-B) + interleaved fat wd-transpose ============
// 128 rows x 128 cols(G)+128(U), waves 2x2 (64x64 each). X single-buffered
// (16K), G/U double-buffered (2x16K each) = 80K LDS -> 2 blocks/CU.
// Per K-tile: issue GU(t+1) dma -> compute(t) -> barrier (GU drain overlapped)
// -> stage X(t+1) -> barrier.
__launch_bounds__(256, 2)
__global__ void gemm1p_kernel(const unsigned short* __restrict__ hsb,
                              const unsigned short* __restrict__ wgT,
                              const unsigned short* __restrict__ wuT,
                              const int* __restrict__ offs,
                              const int* __restrict__ row_tok,
                              unsigned short* __restrict__ act,
                              const float* __restrict__ wd,
                              unsigned short* __restrict__ wdT,
                              int fat) {
    int gid = blockIdx.x;
    if (fat) {
        int q = gid / 6, r = gid - q * 6;
        if (r == 5) {   // transpose role: 1-in-6 of dispatch order, grid-stride
            for (int t = q; t < TRB; t += FATB)
                transpose_cvt_dev(wd, wdT, IDIM, HDIM, 32, t);
            return;
        }
        gid = 5 * q + r;   // dense 0..G1B-1
    }

    __shared__ char lds[81920];
    char* Xb = lds;                 // 16K

    int rt = gid >> 3;
    int nt = gid & 7;
    int total = offs[NEXP];
    if (rt * BM >= total) return;
    int e = 0;
    while (offs[e + 1] <= rt * BM) e++;

    int tid = threadIdx.x, l = tid & 63, wv = tid >> 6;
    int wm = wv >> 1, wn = wv & 1;

    // per-lane pre-swizzled source chunk within a 128B row
    unsigned srcChunk = ((l & 7) * 16) ^ ((l >> 3) << 4);

    unsigned xoff[4], goff[4];
#pragma unroll
    for (int i = 0; i < 4; ++i) {
        int r = i * 32 + wv * 8 + (l >> 3);
        int tok = row_tok[rt * BM + r];
        if (tok < 0) tok = 0;
        xoff[i] = (unsigned)tok * (HDIM * 2) + srcChunk;
        unsigned wrow = (unsigned)e * IDIM + nt * BN + r;
        goff[i] = wrow * (HDIM * 2) + srcChunk;
    }

    f4 accG[4][4], accU[4][4];
#pragma unroll
    for (int mi = 0; mi < 4; ++mi)
#pragma unroll
        for (int ni = 0; ni < 4; ++ni) { accG[mi][ni] = (f4)0.0f; accU[mi][ni] = (f4)0.0f; }

    const char* hsc = (const char*)hsb;
    const char* wgc = (const char*)wgT;
    const char* wuc = (const char*)wuT;

#define STAGEGU(KT, GD, UD) {                                               \
    unsigned kby_ = (unsigned)(KT) * 128;                                   \
    _Pragma("unroll")                                                       \
    for (int i = 0; i < 4; ++i)                                             \
        gload16(wgc + (size_t)goff[i] + kby_, (GD) + i * 4096 + wv * 1024); \
    _Pragma("unroll")                                                       \
    for (int i = 0; i < 4; ++i)                                             \
        gload16(wuc + (size_t)goff[i] + kby_, (UD) + i * 4096 + wv * 1024); \
    }

#define STAGEX1(KT) {                                                       \
    unsigned kby_ = (unsigned)(KT) * 128;                                   \
    _Pragma("unroll")                                                       \
    for (int i = 0; i < 4; ++i)                                             \
        gload16(hsc + (size_t)xoff[i] + kby_, Xb + i * 4096 + wv * 1024);   \
    }

    // prologue: tile 0
    STAGEGU(0, lds + 16384, lds + 49152);
    STAGEX1(0);
    __syncthreads();

    const int NT = HDIM / BK;   // 32
    for (int kt = 0; kt < NT; ++kt) {
        char* Gc = (kt & 1) ? (lds + 32768) : (lds + 16384);
        char* Gn = (kt & 1) ? (lds + 16384) : (lds + 32768);
        char* Uc = (kt & 1) ? (lds + 65536) : (lds + 49152);
        char* Un = (kt & 1) ? (lds + 49152) : (lds + 65536);

        if (kt < NT - 1) STAGEGU(kt + 1, Gn, Un);   // W dma issued BEFORE compute

#pragma unroll
        for (int ks = 0; ks < 2; ++ks) {
            int kb = ks * 64 + ((l >> 4) << 4);
            bh8 a[4], g[4], u[4];
#pragma unroll
            for (int mi = 0; mi < 4; ++mi)
                a[mi] = *(const bh8*)(Xb + swz(wm * 64 + mi * 16 + (l & 15), kb));
#pragma unroll
            for (int ni = 0; ni < 4; ++ni) {
                int nr = wn * 64 + ni * 16 + (l & 15);
                g[ni] = *(const bh8*)(Gc + swz(nr, kb));
                u[ni] = *(const bh8*)(Uc + swz(nr, kb));
            }
#pragma unroll
            for (int mi = 0; mi < 4; ++mi)
#pragma unroll
                for (int ni = 0; ni < 4; ++ni) {
                    accG[mi][ni] = __builtin_amdgcn_mfma_f32_16x16x32_bf16(a[mi], g[ni], accG[mi][ni], 0, 0, 0);
                    accU[mi][ni] = __builtin_amdgcn_mfma_f32_16x16x32_bf16(a[mi], u[ni], accU[mi][ni], 0, 0, 0);
                }
        }
        __syncthreads();                 // GU(t+1) drain had full compute to land; X reads done
        if (kt < NT - 1) {
            STAGEX1(kt + 1);             // X into now-free single buffer
            __syncthreads();             // X ready for compute(t+1)
        }
    }

    // epilogue: gelu(g)*u -> bf16 act, pre-swizzled byte layout
    char* actc = (char*)act;
#pragma unroll
    for (int mi = 0; mi < 4; ++mi) {
#pragma unroll
        for (int i = 0; i < 4; ++i) {
            int r = rt * BM + wm * 64 + mi * 16 + ((l >> 4) << 2) + i;
            size_t rowbase = (size_t)r * (IDIM * 2);
            int rs = (r & 7) << 4;
#pragma unroll
            for (int ni = 0; ni < 4; ++ni) {
                int col = nt * BN + wn * 64 + ni * 16 + (l & 15);
                float gv = accG[mi][ni][i], uv = accU[mi][ni][i];
                float gl = 0.5f * gv * (1.0f + erff(gv * 0.70710678118654752f));
                *(unsigned short*)(actc + rowbase + ((col * 2) ^ rs)) = f2bf(gl * uv);
            }
        }
    }
#undef STAGEGU
#undef STAGEX1
}

// ============ GEMM2 (2-phase-B): out[tok] += w * (act @ WdT^T) ============
// 128 rows x 256 cols, waves 2x2 (64x128). act single-buffered (16K),
// Wd double-buffered (2x32K) = 80K LDS -> 2 blocks/CU.
__launch_bounds__(256, 2)
__global__ void gemm2p_kernel(const unsigned short* __restrict__ act,
                              const unsigned short* __restrict__ wdT,
                              const int* __restrict__ offs,
                              const int* __restrict__ row_tok,
                              const float* __restrict__ row_w,
                              float* __restrict__ out) {
    __shared__ char lds[81920];
    char* Xb = lds;                 // 16K

    int rt = blockIdx.x >> 3;
    int nt = blockIdx.x & 7;   // 2048 / 256
    int total = offs[NEXP];
    if (rt * BM >= total) return;
    int e = 0;
    while (offs[e + 1] <= rt * BM) e++;

    int tid = threadIdx.x, l = tid & 63, wv = tid >> 6;
    int wm = wv >> 1, wn = wv & 1;

    unsigned srcChunk = ((l & 7) * 16) ^ ((l >> 3) << 4);

    unsigned aoff[4];
#pragma unroll
    for (int i = 0; i < 4; ++i) {
        int r = i * 32 + wv * 8 + (l >> 3);
        aoff[i] = (unsigned)(rt * BM + r) * (IDIM * 2) + (l & 7) * 16;  // act pre-swizzled: linear source
    }
    unsigned doff[8];
#pragma unroll
    for (int i = 0; i < 8; ++i) {
        int r = i * 32 + wv * 8 + (l >> 3);
        doff[i] = ((unsigned)e * HDIM + nt * 256 + r) * (IDIM * 2) + srcChunk;
    }

    f4 acc[4][8];
#pragma unroll
    for (int mi = 0; mi < 4; ++mi)
#pragma unroll
        for (int ni = 0; ni < 8; ++ni) acc[mi][ni] = (f4)0.0f;

    const char* actc = (const char*)act;
    const char* wdc = (const char*)wdT;

#define STAGED(KT, DD) {                                                    \
    unsigned kby_ = (unsigned)(KT) * 128;                                   \
    _Pragma("unroll")                                                       \
    for (int i = 0; i < 8; ++i)                                             \
        gload16(wdc + (size_t)doff[i] + kby_, (DD) + i * 4096 + wv * 1024); \
    }

#define STAGEA(KT) {                                                        \
    unsigned kby_ = (unsigned)(KT) * 128;                                   \
    _Pragma("unroll")                                                       \
    for (int i = 0; i < 4; ++i)                                             \
        gload16(actc + (size_t)aoff[i] + kby_, Xb + i * 4096 + wv * 1024);  \
    }

    STAGED(0, lds + 16384);
    STAGEA(0);
    __syncthreads();

    const int NT = IDIM / BK;   // 16
    for (int kt = 0; kt < NT; ++kt) {
        char* Dc = (kt & 1) ? (lds + 49152) : (lds + 16384);
        char* Dn = (kt & 1) ? (lds + 16384) : (lds + 49152);

        if (kt < NT - 1) STAGED(kt + 1, Dn);

#pragma unroll
        for (int ks = 0; ks < 2; ++ks) {
            int kb = ks * 64 + ((l >> 4) << 4);
            bh8 a[4], b[8];
#pragma unroll
            for (int mi = 0; mi < 4; ++mi)
                a[mi] = *(const bh8*)(Xb + swz(wm * 64 + mi * 16 + (l & 15), kb));
#pragma unroll
            for (int ni = 0; ni < 8; ++ni)
                b[ni] = *(const bh8*)(Dc + swz(wn * 128 + ni * 16 + (l & 15), kb));
#pragma unroll
            for (int mi = 0; mi < 4; ++mi)
#pragma unroll
                for (int ni = 0; ni < 8; ++ni)
                    acc[mi][ni] = __builtin_amdgcn_mfma_f32_16x16x32_bf16(a[mi], b[ni], acc[mi][ni], 0, 0, 0);
        }
        __syncthreads();
        if (kt < NT - 1) {
            STAGEA(kt + 1);
            __syncthreads();
        }
    }

    // epilogue: scale by routing weight, atomic accumulate
#pragma unroll
    for (int mi = 0; mi < 4; ++mi) {
#pragma unroll
        for (int i = 0; i < 4; ++i) {
            int r = rt * BM + wm * 64 + mi * 16 + ((l >> 4) << 2) + i;
            int tok = row_tok[r];
            if (tok < 0) continue;
            float w = row_w[r];
            float* op = out + (size_t)tok * HDIM + nt * 256 + wn * 128 + (l & 15);
#pragma unroll
            for (int ni = 0; ni < 8; ++ni)
                atomicAdd(op + ni * 16, acc[mi][ni][i] * w);
        }
    }
#undef STAGED
#undef STAGEA
}

// ---------------- launch ----------------
// ws layout:
//   [0,512): counts(128) | cursor(128) | offs(132)
//   512:            row_tok  CAP*4
//   512+CAP*4:      row_w    CAP*4
//   +:              act      CAP*IDIM*2     (41.9 MB)
//   +actB:          hs_bf16  T*H*2          (33.6 MB)
//   +hsB:           wgT      E*I*H*2        (134.2 MB)
//   +wTB:           wuT      E*I*H*2        (134.2 MB)   -> needSerial = 344.1 MB
//   +wTB:           wdT      E*I*H*2        (134.2 MB)   -> needFat    = 478.3 MB

extern "C" void kernel_launch(void* const* d_in, const int* in_sizes, int n_in,
                              void* d_out, int out_size, void* d_ws, size_t ws_size,
                              hipStream_t stream) {
    const float* hs     = (const float*)d_in[0];
    const float* logits = (const float*)d_in[1];
    const float* scale  = (const float*)d_in[2];
    const float* wg     = (const float*)d_in[3];
    const float* wu     = (const float*)d_in[4];
    const float* wd     = (const float*)d_in[5];
    float* out = (float*)d_out;

    char* ws = (char*)d_ws;
    int*   counts  = (int*)ws;
    int*   cursor  = counts + 32;
    int*   offs    = cursor + 32;
    int*   row_tok = (int*)(ws + 512);
    float* row_w   = (float*)(ws + 512 + (size_t)CAP * 4);

    size_t base = 512 + (size_t)CAP * 8;
    size_t actB = (size_t)CAP * IDIM * 2;
    size_t hsB  = (size_t)T_TOK * HDIM * 2;
    size_t wTB  = (size_t)NEXP * IDIM * HDIM * 2;

    unsigned short* act = (unsigned short*)(ws + base);
    unsigned short* hsb = (unsigned short*)(ws + base + actB);
    unsigned short* wgT = (unsigned short*)(ws + base + actB + hsB);
    unsigned short* wuT = (unsigned short*)(ws + base + actB + hsB + wTB);
    unsigned short* wdT = (unsigned short*)(ws + base + actB + hsB + 2 * wTB);

    size_t needFat = base + actB + hsB + 3 * wTB;
    bool fat = (ws_size >= needFat);

    hipMemsetAsync(counts, 0, 512, stream);
    hipMemsetAsync(row_tok, 0xFF, (size_t)CAP * 4, stream);
    hipMemsetAsync(out, 0, (size_t)out_size * sizeof(float), stream);

    route_count_kernel<<<T_TOK / 256, 256, 0, stream>>>(logits, counts);
    offsets_kernel<<<1, 64, 0, stream>>>(counts, offs);
    route_scatter_kernel<<<T_TOK / 256, 256, 0, stream>>>(logits, scale, offs, cursor, row_tok, row_w);

    prep_all<<<CVB + 2 * TRB, 256, 0, stream>>>(hs, hsb, wg, wgT, wu, wuT);

    if (fat) {
        gemm1p_kernel<<<G1GRID, 256, 0, stream>>>(hsb, wgT, wuT, offs, row_tok, act, wd, wdT, 1);
        gemm2p_kernel<<<MAX_RT * 8, 256, 0, stream>>>(act, wdT, offs, row_tok, row_w, out);
    } else {
        gemm1p_kernel<<<G1B, 256, 0, stream>>>(hsb, wgT, wuT, offs, row_tok, act, wd, wgT /*unused*/, 0);
        transpose_wd_kernel<<<TRB, 256, 0, stream>>>(wd, wgT);   // reuse wgT region
        gemm2p_kernel<<<MAX_RT * 8, 256, 0, stream>>>(act, wgT, offs, row_tok, row_w, out);
    }
}

// Round 8
// 744.005 us; speedup vs baseline: 1.4730x; 1.0736x over previous
//
#include <hip/hip_runtime.h>

#define T_TOK 8192
#define HDIM  2048
#define NEXP  32
#define IDIM  1024

#define BM 256
#define BK 64
#define CAP (T_TOK*2 + NEXP*BM)   // 24576 max padded rows
#define MAX_RT (CAP/BM)           // 96 row tiles max
#define TRB (NEXP*512)            // 16384 transpose tiles per matrix
#define CVB 8192                  // cvt_hs blocks

typedef __attribute__((ext_vector_type(8))) short bh8;   // 8 bf16 (4 VGPR) MFMA A/B frag
typedef __attribute__((ext_vector_type(4))) float f4;    // MFMA C/D frag

// fp32 -> bf16 round-to-nearest-even (bit pattern)
__device__ __forceinline__ unsigned short f2bf(float f) {
    unsigned u = __builtin_bit_cast(unsigned, f);
    u += 0x7FFFu + ((u >> 16) & 1u);
    return (unsigned short)(u >> 16);
}

// XOR swizzle: 128-byte LDS rows, byte ^= (row&7)<<4.  (proven 0-conflict, rounds 1-2)
__device__ __forceinline__ int swz(int row, int kb) {
    return row * 128 + (kb ^ ((row & 7) << 4));
}

// async 16B global->LDS (dest = wave-uniform base + lane*16, source per-lane)
__device__ __forceinline__ void gload16(const void* g, void* l) {
    __builtin_amdgcn_global_load_lds(
        (const __attribute__((address_space(1))) unsigned int*)g,
        (__attribute__((address_space(3))) unsigned int*)l,
        16, 0, 0);
}

// ---------------- routing ----------------

__device__ __forceinline__ void top2(const float* __restrict__ l,
                                     int& b1, float& v1, int& b2, float& v2) {
    v1 = -1e30f; b1 = 0;
#pragma unroll
    for (int e = 0; e < NEXP; ++e) { float v = l[e]; if (v > v1) { v1 = v; b1 = e; } }
    v2 = -1e30f; b2 = 0;
#pragma unroll
    for (int e = 0; e < NEXP; ++e) { if (e == b1) continue; float v = l[e]; if (v > v2) { v2 = v; b2 = e; } }
}

__global__ void route_count_kernel(const float* __restrict__ logits, int* __restrict__ counts) {
    int t = blockIdx.x * blockDim.x + threadIdx.x;
    if (t >= T_TOK) return;
    int b1, b2; float v1, v2;
    top2(logits + (size_t)t * NEXP, b1, v1, b2, v2);
    atomicAdd(&counts[b1], 1);
    atomicAdd(&counts[b2], 1);
}

__global__ void offsets_kernel(const int* __restrict__ counts, int* __restrict__ offs) {
    if (threadIdx.x == 0) {
        int o = 0;
        for (int e = 0; e < NEXP; ++e) { offs[e] = o; o += (counts[e] + BM - 1) & ~(BM - 1); }
        offs[NEXP] = o;
    }
}

__global__ void route_scatter_kernel(const float* __restrict__ logits,
                                     const float* __restrict__ scale,
                                     const int* __restrict__ offs,
                                     int* __restrict__ cursor,
                                     int* __restrict__ row_tok,
                                     float* __restrict__ row_w) {
    int t = blockIdx.x * blockDim.x + threadIdx.x;
    if (t >= T_TOK) return;
    int b1, b2; float v1, v2;
    top2(logits + (size_t)t * NEXP, b1, v1, b2, v2);
    float e2 = expf(v2 - v1);
    float inv = 1.0f / (1.0f + e2);
    float w1 = scale[b1] * inv;
    float w2 = scale[b2] * e2 * inv;
    int p1 = offs[b1] + atomicAdd(&cursor[b1], 1);
    row_tok[p1] = t; row_w[p1] = w1;
    int p2 = offs[b2] + atomicAdd(&cursor[b2], 1);
    row_tok[p2] = t; row_w[p2] = w2;
}

// ---------------- prep: convert + transpose ----------------

// [E][K][N] fp32 -> [E][N][K] bf16, 64x64 tiles, register-only transpose.
__device__ __forceinline__ void transpose_cvt_dev(const float* __restrict__ in,
                                                  unsigned short* __restrict__ out,
                                                  int K, int N, int tilesN, int bid) {
    int e = bid >> 9;            // 512 tiles per expert for both shapes
    int tile = bid & 511;
    int k0 = (tile / tilesN) * 64;
    int n0 = (tile % tilesN) * 64;
    const float* src = in + (size_t)e * K * N;
    unsigned short* dst = out + (size_t)e * K * N;
    int tid = threadIdx.x, l = tid & 63, w = tid >> 6;
    int n = n0 + w * 16 + (l >> 2);
#pragma unroll
    for (int p = 0; p < 2; ++p) {
        int kc = k0 + p * 32 + (l & 3) * 8;
        const float* s = src + (size_t)kc * N + n;
        bh8 v;
#pragma unroll
        for (int j = 0; j < 8; ++j) v[j] = (short)f2bf(s[(size_t)j * N]);
        *(bh8*)(dst + (size_t)n * K + kc) = v;
    }
}

// Fused: cvt_hs | wg transpose | wu transpose | (optional) wd transpose.
// Grid = CVB + 2*TRB (fallback) or CVB + 3*TRB (full).
__global__ void prep_all(const float* __restrict__ hs, unsigned short* __restrict__ hsb,
                         const float* __restrict__ wg, unsigned short* __restrict__ wgT,
                         const float* __restrict__ wu, unsigned short* __restrict__ wuT,
                         const float* __restrict__ wd, unsigned short* __restrict__ wdT) {
    int b = blockIdx.x;
    if (b < CVB) {
        size_t i = ((size_t)b * 256 + threadIdx.x) * 8;
        float4 a = *(const float4*)(hs + i);
        float4 c = *(const float4*)(hs + i + 4);
        bh8 v;
        v[0] = (short)f2bf(a.x); v[1] = (short)f2bf(a.y);
        v[2] = (short)f2bf(a.z); v[3] = (short)f2bf(a.w);
        v[4] = (short)f2bf(c.x); v[5] = (short)f2bf(c.y);
        v[6] = (short)f2bf(c.z); v[7] = (short)f2bf(c.w);
        *(bh8*)(hsb + i) = v;
    } else if (b < CVB + TRB) {
        transpose_cvt_dev(wg, wgT, HDIM, IDIM, 16, b - CVB);
    } else if (b < CVB + 2 * TRB) {
        transpose_cvt_dev(wu, wuT, HDIM, IDIM, 16, b - CVB - TRB);
    } else {
        transpose_cvt_dev(wd, wdT, IDIM, HDIM, 32, b - CVB - 2 * TRB);
    }
}

// standalone wd transpose (serial fallback path)
__global__ void transpose_wd_kernel(const float* __restrict__ wd, unsigned short* __restrict__ wdT) {
    transpose_cvt_dev(wd, wdT, IDIM, HDIM, 32, blockIdx.x);
}

// ============ GEMM1 (T3-minimum): act = gelu(X@Wg) * (X@Wu) ============
// 512 threads, BM=256 x BN=128 (G and U each). Waves 4m x 2n, wave = 64r x 64c dual.
// ALL operands gload16 double-buffered; STAGE(t+1) issued BEFORE compute(t);
// ONE barrier per K-tile (vmcnt drain lands after a full compute phase).
__launch_bounds__(512, 2)
__global__ void gemm1q_kernel(const unsigned short* __restrict__ hsb,
                              const unsigned short* __restrict__ wgT,
                              const unsigned short* __restrict__ wuT,
                              const int* __restrict__ offs,
                              const int* __restrict__ row_tok,
                              unsigned short* __restrict__ act) {
    __shared__ char lds[131072];
    // X0 @0 (32K) | X1 @32768 | G0 @65536 (16K) | G1 @81920 | U0 @98304 | U1 @114688

    int gid = blockIdx.x;
    int rt = gid >> 3;
    int nt = gid & 7;          // IDIM/128
    if (rt * BM >= offs[NEXP]) return;
    int e = 0;
    while (offs[e + 1] <= rt * BM) e++;

    int tid = threadIdx.x, l = tid & 63, w = tid >> 6;
    int wm = w >> 1, wn = w & 1;

    // pre-swizzled per-lane source chunk within a 128B row
    unsigned srcx = ((l & 7) * 16) ^ ((l >> 3) << 4);

    size_t xoff[4];
#pragma unroll
    for (int i = 0; i < 4; ++i) {
        int tok = row_tok[rt * BM + i * 64 + w * 8 + (l >> 3)];
        if (tok < 0) tok = 0;
        xoff[i] = (size_t)tok * (HDIM * 2) + srcx;
    }
    size_t goff[2];
#pragma unroll
    for (int i = 0; i < 2; ++i) {
        int r = i * 64 + w * 8 + (l >> 3);   // 0..127
        goff[i] = ((size_t)e * IDIM + nt * 128 + r) * (HDIM * 2) + srcx;
    }

    const char* hsc = (const char*)hsb;
    const char* wgc = (const char*)wgT;
    const char* wuc = (const char*)wuT;

    f4 accG[4][4], accU[4][4];
#pragma unroll
    for (int mi = 0; mi < 4; ++mi)
#pragma unroll
        for (int ni = 0; ni < 4; ++ni) { accG[mi][ni] = (f4)0.0f; accU[mi][ni] = (f4)0.0f; }

#define STAGE1(KT, XD, GD, UD) {                                            \
    size_t kby_ = (size_t)(KT) * 128;                                       \
    _Pragma("unroll")                                                       \
    for (int i = 0; i < 4; ++i)                                             \
        gload16(hsc + xoff[i] + kby_, (XD) + i * 8192 + w * 1024);          \
    _Pragma("unroll")                                                       \
    for (int i = 0; i < 2; ++i)                                             \
        gload16(wgc + goff[i] + kby_, (GD) + i * 8192 + w * 1024);          \
    _Pragma("unroll")                                                       \
    for (int i = 0; i < 2; ++i)                                             \
        gload16(wuc + goff[i] + kby_, (UD) + i * 8192 + w * 1024);          \
    }

    STAGE1(0, lds, lds + 65536, lds + 98304);
    __syncthreads();

    const int NT = HDIM / BK;   // 32
    for (int kt = 0; kt < NT; ++kt) {
        char* Xc = (kt & 1) ? (lds + 32768) : lds;
        char* Xn = (kt & 1) ? lds : (lds + 32768);
        char* Gc = (kt & 1) ? (lds + 81920) : (lds + 65536);
        char* Gn = (kt & 1) ? (lds + 65536) : (lds + 81920);
        char* Uc = (kt & 1) ? (lds + 114688) : (lds + 98304);
        char* Un = (kt & 1) ? (lds + 98304) : (lds + 114688);

        if (kt < NT - 1) STAGE1(kt + 1, Xn, Gn, Un);   // issued before compute

#pragma unroll
        for (int ks = 0; ks < 2; ++ks) {
            int kb = ks * 64 + ((l >> 4) << 4);
            bh8 a[4], g[4], u[4];
#pragma unroll
            for (int mi = 0; mi < 4; ++mi)
                a[mi] = *(const bh8*)(Xc + swz(wm * 64 + mi * 16 + (l & 15), kb));
#pragma unroll
            for (int ni = 0; ni < 4; ++ni) {
                int nr = wn * 64 + ni * 16 + (l & 15);
                g[ni] = *(const bh8*)(Gc + swz(nr, kb));
                u[ni] = *(const bh8*)(Uc + swz(nr, kb));
            }
#pragma unroll
            for (int mi = 0; mi < 4; ++mi)
#pragma unroll
                for (int ni = 0; ni < 4; ++ni) {
                    accG[mi][ni] = __builtin_amdgcn_mfma_f32_16x16x32_bf16(a[mi], g[ni], accG[mi][ni], 0, 0, 0);
                    accU[mi][ni] = __builtin_amdgcn_mfma_f32_16x16x32_bf16(a[mi], u[ni], accU[mi][ni], 0, 0, 0);
                }
        }
        __syncthreads();   // drains STAGE(kt+1) vmem (issued a full compute ago)
    }

    // epilogue: gelu(g)*u -> bf16 act, pre-swizzled byte layout
    char* actc = (char*)act;
#pragma unroll
    for (int mi = 0; mi < 4; ++mi) {
#pragma unroll
        for (int i = 0; i < 4; ++i) {
            int r = rt * BM + wm * 64 + mi * 16 + ((l >> 4) << 2) + i;
            size_t rowbase = (size_t)r * (IDIM * 2);
            int rs = (r & 7) << 4;
#pragma unroll
            for (int ni = 0; ni < 4; ++ni) {
                int col = nt * 128 + wn * 64 + ni * 16 + (l & 15);
                float gv = accG[mi][ni][i], uv = accU[mi][ni][i];
                float gl = 0.5f * gv * (1.0f + erff(gv * 0.70710678118654752f));
                *(unsigned short*)(actc + rowbase + ((col * 2) ^ rs)) = f2bf(gl * uv);
            }
        }
    }
#undef STAGE1
}

// ============ GEMM2 (T3-minimum): out[tok] += w * (act @ WdT^T) ============
// 512 threads, BM=256 x BN=256. Waves 4m x 2n, wave = 64r x 128c.
__launch_bounds__(512, 2)
__global__ void gemm2q_kernel(const unsigned short* __restrict__ act,
                              const unsigned short* __restrict__ wdT,
                              const int* __restrict__ offs,
                              const int* __restrict__ row_tok,
                              const float* __restrict__ row_w,
                              float* __restrict__ out) {
    __shared__ char lds[131072];
    // X0 @0 (32K) | X1 @32768 | D0 @65536 (32K) | D1 @98304

    int gid = blockIdx.x;
    int rt = gid >> 3;
    int nt = gid & 7;          // HDIM/256
    if (rt * BM >= offs[NEXP]) return;
    int e = 0;
    while (offs[e + 1] <= rt * BM) e++;

    int tid = threadIdx.x, l = tid & 63, w = tid >> 6;
    int wm = w >> 1, wn = w & 1;

    unsigned srcx = ((l & 7) * 16) ^ ((l >> 3) << 4);

    size_t aoff[4];
#pragma unroll
    for (int i = 0; i < 4; ++i)
        aoff[i] = (size_t)(rt * BM + i * 64 + w * 8 + (l >> 3)) * (IDIM * 2) + (l & 7) * 16;
    size_t doff[4];
#pragma unroll
    for (int i = 0; i < 4; ++i) {
        int r = i * 64 + w * 8 + (l >> 3);   // 0..255
        doff[i] = ((size_t)e * HDIM + nt * 256 + r) * (IDIM * 2) + srcx;
    }

    const char* actc = (const char*)act;
    const char* wdc = (const char*)wdT;

    f4 acc[4][8];
#pragma unroll
    for (int mi = 0; mi < 4; ++mi)
#pragma unroll
        for (int ni = 0; ni < 8; ++ni) acc[mi][ni] = (f4)0.0f;

#define STAGE2(KT, XD, DD) {                                                \
    size_t kby_ = (size_t)(KT) * 128;                                       \
    _Pragma("unroll")                                                       \
    for (int i = 0; i < 4; ++i)                                             \
        gload16(actc + aoff[i] + kby_, (XD) + i * 8192 + w * 1024);         \
    _Pragma("unroll")                                                       \
    for (int i = 0; i < 4; ++i)                                             \
        gload16(wdc + doff[i] + kby_, (DD) + i * 8192 + w * 1024);          \
    }

    STAGE2(0, lds, lds + 65536);
    __syncthreads();

    const int NT = IDIM / BK;   // 16
    for (int kt = 0; kt < NT; ++kt) {
        char* Xc = (kt & 1) ? (lds + 32768) : lds;
        char* Xn = (kt & 1) ? lds : (lds + 32768);
        char* Dc = (kt & 1) ? (lds + 98304) : (lds + 65536);
        char* Dn = (kt & 1) ? (lds + 65536) : (lds + 98304);

        if (kt < NT - 1) STAGE2(kt + 1, Xn, Dn);

#pragma unroll
        for (int ks = 0; ks < 2; ++ks) {
            int kb = ks * 64 + ((l >> 4) << 4);
            bh8 a[4], b[8];
#pragma unroll
            for (int mi = 0; mi < 4; ++mi)
                a[mi] = *(const bh8*)(Xc + swz(wm * 64 + mi * 16 + (l & 15), kb));
#pragma unroll
            for (int ni = 0; ni < 8; ++ni)
                b[ni] = *(const bh8*)(Dc + swz(wn * 128 + ni * 16 + (l & 15), kb));
#pragma unroll
            for (int mi = 0; mi < 4; ++mi)
#pragma unroll
                for (int ni = 0; ni < 8; ++ni)
                    acc[mi][ni] = __builtin_amdgcn_mfma_f32_16x16x32_bf16(a[mi], b[ni], acc[mi][ni], 0, 0, 0);
        }
        __syncthreads();
    }

    // epilogue: scale by routing weight, atomic accumulate
#pragma unroll
    for (int mi = 0; mi < 4; ++mi) {
#pragma unroll
        for (int i = 0; i < 4; ++i) {
            int r = rt * BM + wm * 64 + mi * 16 + ((l >> 4) << 2) + i;
            int tok = row_tok[r];
            if (tok < 0) continue;
            float wgt = row_w[r];
            float* op = out + (size_t)tok * HDIM + nt * 256 + wn * 128 + (l & 15);
#pragma unroll
            for (int ni = 0; ni < 8; ++ni)
                atomicAdd(op + ni * 16, acc[mi][ni][i] * wgt);
        }
    }
#undef STAGE2
}

// ---------------- launch ----------------
// ws layout:
//   [0,512): counts(128) | cursor(128) | offs(132)
//   512:            row_tok  CAP*4
//   512+CAP*4:      row_w    CAP*4
//   +:              act      CAP*IDIM*2     (50.3 MB)
//   +actB:          hs_bf16  T*H*2          (33.6 MB)
//   +hsB:           wgT      E*I*H*2        (134.2 MB)
//   +wTB:           wuT      E*I*H*2        (134.2 MB)   -> need2 = 352.7 MB
//   +wTB:           wdT      E*I*H*2        (134.2 MB)   -> need3 = 486.9 MB

extern "C" void kernel_launch(void* const* d_in, const int* in_sizes, int n_in,
                              void* d_out, int out_size, void* d_ws, size_t ws_size,
                              hipStream_t stream) {
    const float* hs     = (const float*)d_in[0];
    const float* logits = (const float*)d_in[1];
    const float* scale  = (const float*)d_in[2];
    const float* wg     = (const float*)d_in[3];
    const float* wu     = (const float*)d_in[4];
    const float* wd     = (const float*)d_in[5];
    float* out = (float*)d_out;

    char* ws = (char*)d_ws;
    int*   counts  = (int*)ws;
    int*   cursor  = counts + 32;
    int*   offs    = cursor + 32;
    int*   row_tok = (int*)(ws + 512);
    float* row_w   = (float*)(ws + 512 + (size_t)CAP * 4);

    size_t base = 512 + (size_t)CAP * 8;
    size_t actB = (size_t)CAP * IDIM * 2;
    size_t hsB  = (size_t)T_TOK * HDIM * 2;
    size_t wTB  = (size_t)NEXP * IDIM * HDIM * 2;

    unsigned short* act = (unsigned short*)(ws + base);
    unsigned short* hsb = (unsigned short*)(ws + base + actB);
    unsigned short* wgT = (unsigned short*)(ws + base + actB + hsB);
    unsigned short* wuT = (unsigned short*)(ws + base + actB + hsB + wTB);
    unsigned short* wdT = (unsigned short*)(ws + base + actB + hsB + 2 * wTB);

    size_t need3 = base + actB + hsB + 3 * wTB;
    bool full = (ws_size >= need3);

    hipMemsetAsync(counts, 0, 512, stream);
    hipMemsetAsync(row_tok, 0xFF, (size_t)CAP * 4, stream);
    hipMemsetAsync(out, 0, (size_t)out_size * sizeof(float), stream);

    route_count_kernel<<<T_TOK / 256, 256, 0, stream>>>(logits, counts);
    offsets_kernel<<<1, 64, 0, stream>>>(counts, offs);
    route_scatter_kernel<<<T_TOK / 256, 256, 0, stream>>>(logits, scale, offs, cursor, row_tok, row_w);

    if (full) {
        prep_all<<<CVB + 3 * TRB, 256, 0, stream>>>(hs, hsb, wg, wgT, wu, wuT, wd, wdT);
        gemm1q_kernel<<<MAX_RT * 8, 512, 0, stream>>>(hsb, wgT, wuT, offs, row_tok, act);
        gemm2q_kernel<<<MAX_RT * 8, 512, 0, stream>>>(act, wdT, offs, row_tok, row_w, out);
    } else {
        prep_all<<<CVB + 2 * TRB, 256, 0, stream>>>(hs, hsb, wg, wgT, wu, wuT, wd, wdT);
        gemm1q_kernel<<<MAX_RT * 8, 512, 0, stream>>>(hsb, wgT, wuT, offs, row_tok, act);
        transpose_wd_kernel<<<TRB, 256, 0, stream>>>(wd, wgT);   // reuse wgT region
        gemm2q_kernel<<<MAX_RT * 8, 512, 0, stream>>>(act, wgT, offs, row_tok, row_w, out);
    }
}

// Round 9
// 723.103 us; speedup vs baseline: 1.5155x; 1.0289x over previous
//
#include <hip/hip_runtime.h>

#define T_TOK 8192
#define HDIM  2048
#define NEXP  32
#define IDIM  1024

#define BM 256
#define BK 64
#define CAP (T_TOK*2 + NEXP*BM)   // 24576 max padded rows
#define MAX_RT (CAP/BM)           // 96 row tiles max
#define TRB (NEXP*512)            // 16384 transpose tiles per matrix
#define CVB 8192                  // cvt_hs blocks

typedef __attribute__((ext_vector_type(8))) short bh8;   // 8 bf16 (4 VGPR) MFMA A/B frag
typedef __attribute__((ext_vector_type(4))) float f4;    // MFMA C/D frag

// fp32 -> bf16 round-to-nearest-even (bit pattern)
__device__ __forceinline__ unsigned short f2bf(float f) {
    unsigned u = __builtin_bit_cast(unsigned, f);
    u += 0x7FFFu + ((u >> 16) & 1u);
    return (unsigned short)(u >> 16);
}

// XOR swizzle: 128-byte LDS rows, byte ^= (row&7)<<4.  (proven 0-conflict, rounds 1-2)
__device__ __forceinline__ int swz(int row, int kb) {
    return row * 128 + (kb ^ ((row & 7) << 4));
}

// async 16B global->LDS (dest = wave-uniform base + lane*16, source per-lane)
__device__ __forceinline__ void gload16(const void* g, void* l) {
    __builtin_amdgcn_global_load_lds(
        (const __attribute__((address_space(1))) unsigned int*)g,
        (__attribute__((address_space(3))) unsigned int*)l,
        16, 0, 0);
}

// ---------------- routing ----------------

__device__ __forceinline__ void top2(const float* __restrict__ l,
                                     int& b1, float& v1, int& b2, float& v2) {
    v1 = -1e30f; b1 = 0;
#pragma unroll
    for (int e = 0; e < NEXP; ++e) { float v = l[e]; if (v > v1) { v1 = v; b1 = e; } }
    v2 = -1e30f; b2 = 0;
#pragma unroll
    for (int e = 0; e < NEXP; ++e) { if (e == b1) continue; float v = l[e]; if (v > v2) { v2 = v; b2 = e; } }
}

__global__ void route_count_kernel(const float* __restrict__ logits, int* __restrict__ counts) {
    int t = blockIdx.x * blockDim.x + threadIdx.x;
    if (t >= T_TOK) return;
    int b1, b2; float v1, v2;
    top2(logits + (size_t)t * NEXP, b1, v1, b2, v2);
    atomicAdd(&counts[b1], 1);
    atomicAdd(&counts[b2], 1);
}

__global__ void offsets_kernel(const int* __restrict__ counts, int* __restrict__ offs) {
    if (threadIdx.x == 0) {
        int o = 0;
        for (int e = 0; e < NEXP; ++e) { offs[e] = o; o += (counts[e] + BM - 1) & ~(BM - 1); }
        offs[NEXP] = o;
    }
}

__global__ void route_scatter_kernel(const float* __restrict__ logits,
                                     const float* __restrict__ scale,
                                     const int* __restrict__ offs,
                                     int* __restrict__ cursor,
                                     int* __restrict__ row_tok,
                                     float* __restrict__ row_w) {
    int t = blockIdx.x * blockDim.x + threadIdx.x;
    if (t >= T_TOK) return;
    int b1, b2; float v1, v2;
    top2(logits + (size_t)t * NEXP, b1, v1, b2, v2);
    float e2 = expf(v2 - v1);
    float inv = 1.0f / (1.0f + e2);
    float w1 = scale[b1] * inv;
    float w2 = scale[b2] * e2 * inv;
    int p1 = offs[b1] + atomicAdd(&cursor[b1], 1);
    row_tok[p1] = t; row_w[p1] = w1;
    int p2 = offs[b2] + atomicAdd(&cursor[b2], 1);
    row_tok[p2] = t; row_w[p2] = w2;
}

// ---------------- prep: convert + transpose (LDS-staged, coalesced both sides) ----------------

// [E][K][N] fp32 -> [E][N][K] bf16, one 64x64 tile per block, 256 threads.
// Phase 1: reads = 4 full rows x 256B contiguous per wave-instruction.
// Phase 2: writes = 8 lanes x 16B = 128B contiguous dst row segments.
// LDS [64][65] fp32 (stride 65 == 1 mod 32): both phases 2-way bank alias = free.
__device__ __forceinline__ void transpose_cvt_dev(const float* __restrict__ in,
                                                  unsigned short* __restrict__ out,
                                                  int K, int N, int tilesN, int bid,
                                                  float* __restrict__ tl) {
    int e = bid >> 9;            // 512 tiles per expert for both shapes
    int tile = bid & 511;
    int k0 = (tile / tilesN) * 64;
    int n0 = (tile % tilesN) * 64;
    const float* src = in + (size_t)e * K * N + (size_t)k0 * N + n0;
    unsigned short* dst = out + (size_t)e * K * N + (size_t)n0 * K + k0;

    int t = threadIdx.x;
    // phase 1: 16 threads per row (float4 each), 16 rows per pass, 4 passes
    int rr = t >> 4, cc = t & 15;
#pragma unroll
    for (int pp = 0; pp < 4; ++pp) {
        int r = rr + pp * 16;
        float4 a = *(const float4*)(src + (size_t)r * N + cc * 4);
        float* d = tl + r * 65 + cc * 4;
        d[0] = a.x; d[1] = a.y; d[2] = a.z; d[3] = a.w;
    }
    __syncthreads();
    // phase 2: 8 threads per dst row (8 k each -> one b128 store), 32 rows per pass
    int n8 = t >> 3, kc = (t & 7) * 8;
#pragma unroll
    for (int nn = 0; nn < 2; ++nn) {
        int n = n8 + nn * 32;
        bh8 v;
#pragma unroll
        for (int j = 0; j < 8; ++j) v[j] = (short)f2bf(tl[(kc + j) * 65 + n]);
        *(bh8*)(dst + (size_t)n * K + kc) = v;
    }
    __syncthreads();   // safe for any future multi-tile reuse of tl
}

// Fused: cvt_hs | wg transpose | wu transpose | (optional) wd transpose.
// Grid = CVB + 2*TRB (fallback) or CVB + 3*TRB (full).
__global__ void prep_all(const float* __restrict__ hs, unsigned short* __restrict__ hsb,
                         const float* __restrict__ wg, unsigned short* __restrict__ wgT,
                         const float* __restrict__ wu, unsigned short* __restrict__ wuT,
                         const float* __restrict__ wd, unsigned short* __restrict__ wdT) {
    __shared__ float tl[64 * 65];
    int b = blockIdx.x;
    if (b < CVB) {
        size_t i = ((size_t)b * 256 + threadIdx.x) * 8;
        float4 a = *(const float4*)(hs + i);
        float4 c = *(const float4*)(hs + i + 4);
        bh8 v;
        v[0] = (short)f2bf(a.x); v[1] = (short)f2bf(a.y);
        v[2] = (short)f2bf(a.z); v[3] = (short)f2bf(a.w);
        v[4] = (short)f2bf(c.x); v[5] = (short)f2bf(c.y);
        v[6] = (short)f2bf(c.z); v[7] = (short)f2bf(c.w);
        *(bh8*)(hsb + i) = v;
    } else if (b < CVB + TRB) {
        transpose_cvt_dev(wg, wgT, HDIM, IDIM, 16, b - CVB, tl);
    } else if (b < CVB + 2 * TRB) {
        transpose_cvt_dev(wu, wuT, HDIM, IDIM, 16, b - CVB - TRB, tl);
    } else {
        transpose_cvt_dev(wd, wdT, IDIM, HDIM, 32, b - CVB - 2 * TRB, tl);
    }
}

// standalone wd transpose (serial fallback path)
__global__ void transpose_wd_kernel(const float* __restrict__ wd, unsigned short* __restrict__ wdT) {
    __shared__ float tl[64 * 65];
    transpose_cvt_dev(wd, wdT, IDIM, HDIM, 32, blockIdx.x, tl);
}

// ============ GEMM1 (T3-minimum): act = gelu(X@Wg) * (X@Wu) ============
// 512 threads, BM=256 x BN=128 (G and U each). Waves 4m x 2n, wave = 64r x 64c dual.
// ALL operands gload16 double-buffered; STAGE(t+1) issued BEFORE compute(t);
// ONE barrier per K-tile (vmcnt drain lands after a full compute phase).
__launch_bounds__(512, 2)
__global__ void gemm1q_kernel(const unsigned short* __restrict__ hsb,
                              const unsigned short* __restrict__ wgT,
                              const unsigned short* __restrict__ wuT,
                              const int* __restrict__ offs,
                              const int* __restrict__ row_tok,
                              unsigned short* __restrict__ act) {
    __shared__ char lds[131072];
    // X0 @0 (32K) | X1 @32768 | G0 @65536 (16K) | G1 @81920 | U0 @98304 | U1 @114688

    int gid = blockIdx.x;
    int rt = gid >> 3;
    int nt = gid & 7;          // IDIM/128
    if (rt * BM >= offs[NEXP]) return;
    int e = 0;
    while (offs[e + 1] <= rt * BM) e++;

    int tid = threadIdx.x, l = tid & 63, w = tid >> 6;
    int wm = w >> 1, wn = w & 1;

    // pre-swizzled per-lane source chunk within a 128B row
    unsigned srcx = ((l & 7) * 16) ^ ((l >> 3) << 4);

    size_t xoff[4];
#pragma unroll
    for (int i = 0; i < 4; ++i) {
        int tok = row_tok[rt * BM + i * 64 + w * 8 + (l >> 3)];
        if (tok < 0) tok = 0;
        xoff[i] = (size_t)tok * (HDIM * 2) + srcx;
    }
    size_t goff[2];
#pragma unroll
    for (int i = 0; i < 2; ++i) {
        int r = i * 64 + w * 8 + (l >> 3);   // 0..127
        goff[i] = ((size_t)e * IDIM + nt * 128 + r) * (HDIM * 2) + srcx;
    }

    const char* hsc = (const char*)hsb;
    const char* wgc = (const char*)wgT;
    const char* wuc = (const char*)wuT;

    f4 accG[4][4], accU[4][4];
#pragma unroll
    for (int mi = 0; mi < 4; ++mi)
#pragma unroll
        for (int ni = 0; ni < 4; ++ni) { accG[mi][ni] = (f4)0.0f; accU[mi][ni] = (f4)0.0f; }

#define STAGE1(KT, XD, GD, UD) {                                            \
    size_t kby_ = (size_t)(KT) * 128;                                       \
    _Pragma("unroll")                                                       \
    for (int i = 0; i < 4; ++i)                                             \
        gload16(hsc + xoff[i] + kby_, (XD) + i * 8192 + w * 1024);          \
    _Pragma("unroll")                                                       \
    for (int i = 0; i < 2; ++i)                                             \
        gload16(wgc + goff[i] + kby_, (GD) + i * 8192 + w * 1024);          \
    _Pragma("unroll")                                                       \
    for (int i = 0; i < 2; ++i)                                             \
        gload16(wuc + goff[i] + kby_, (UD) + i * 8192 + w * 1024);          \
    }

    STAGE1(0, lds, lds + 65536, lds + 98304);
    __syncthreads();

    const int NT = HDIM / BK;   // 32
    for (int kt = 0; kt < NT; ++kt) {
        char* Xc = (kt & 1) ? (lds + 32768) : lds;
        char* Xn = (kt & 1) ? lds : (lds + 32768);
        char* Gc = (kt & 1) ? (lds + 81920) : (lds + 65536);
        char* Gn = (kt & 1) ? (lds + 65536) : (lds + 81920);
        char* Uc = (kt & 1) ? (lds + 114688) : (lds + 98304);
        char* Un = (kt & 1) ? (lds + 98304) : (lds + 114688);

        if (kt < NT - 1) STAGE1(kt + 1, Xn, Gn, Un);   // issued before compute

#pragma unroll
        for (int ks = 0; ks < 2; ++ks) {
            int kb = ks * 64 + ((l >> 4) << 4);
            bh8 a[4], g[4], u[4];
#pragma unroll
            for (int mi = 0; mi < 4; ++mi)
                a[mi] = *(const bh8*)(Xc + swz(wm * 64 + mi * 16 + (l & 15), kb));
#pragma unroll
            for (int ni = 0; ni < 4; ++ni) {
                int nr = wn * 64 + ni * 16 + (l & 15);
                g[ni] = *(const bh8*)(Gc + swz(nr, kb));
                u[ni] = *(const bh8*)(Uc + swz(nr, kb));
            }
#pragma unroll
            for (int mi = 0; mi < 4; ++mi)
#pragma unroll
                for (int ni = 0; ni < 4; ++ni) {
                    accG[mi][ni] = __builtin_amdgcn_mfma_f32_16x16x32_bf16(a[mi], g[ni], accG[mi][ni], 0, 0, 0);
                    accU[mi][ni] = __builtin_amdgcn_mfma_f32_16x16x32_bf16(a[mi], u[ni], accU[mi][ni], 0, 0, 0);
                }
        }
        __syncthreads();   // drains STAGE(kt+1) vmem (issued a full compute ago)
    }

    // epilogue: gelu(g)*u -> bf16 act, pre-swizzled byte layout
    char* actc = (char*)act;
#pragma unroll
    for (int mi = 0; mi < 4; ++mi) {
#pragma unroll
        for (int i = 0; i < 4; ++i) {
            int r = rt * BM + wm * 64 + mi * 16 + ((l >> 4) << 2) + i;
            size_t rowbase = (size_t)r * (IDIM * 2);
            int rs = (r & 7) << 4;
#pragma unroll
            for (int ni = 0; ni < 4; ++ni) {
                int col = nt * 128 + wn * 64 + ni * 16 + (l & 15);
                float gv = accG[mi][ni][i], uv = accU[mi][ni][i];
                float gl = 0.5f * gv * (1.0f + erff(gv * 0.70710678118654752f));
                *(unsigned short*)(actc + rowbase + ((col * 2) ^ rs)) = f2bf(gl * uv);
            }
        }
    }
#undef STAGE1
}

// ============ GEMM2 (T3-minimum): out[tok] += w * (act @ WdT^T) ============
// 512 threads, BM=256 x BN=256. Waves 4m x 2n, wave = 64r x 128c.
__launch_bounds__(512, 2)
__global__ void gemm2q_kernel(const unsigned short* __restrict__ act,
                              const unsigned short* __restrict__ wdT,
                              const int* __restrict__ offs,
                              const int* __restrict__ row_tok,
                              const float* __restrict__ row_w,
                              float* __restrict__ out) {
    __shared__ char lds[131072];
    // X0 @0 (32K) | X1 @32768 | D0 @65536 (32K) | D1 @98304

    int gid = blockIdx.x;
    int rt = gid >> 3;
    int nt = gid & 7;          // HDIM/256
    if (rt * BM >= offs[NEXP]) return;
    int e = 0;
    while (offs[e + 1] <= rt * BM) e++;

    int tid = threadIdx.x, l = tid & 63, w = tid >> 6;
    int wm = w >> 1, wn = w & 1;

    unsigned srcx = ((l & 7) * 16) ^ ((l >> 3) << 4);

    size_t aoff[4];
#pragma unroll
    for (int i = 0; i < 4; ++i)
        aoff[i] = (size_t)(rt * BM + i * 64 + w * 8 + (l >> 3)) * (IDIM * 2) + (l & 7) * 16;
    size_t doff[4];
#pragma unroll
    for (int i = 0; i < 4; ++i) {
        int r = i * 64 + w * 8 + (l >> 3);   // 0..255
        doff[i] = ((size_t)e * HDIM + nt * 256 + r) * (IDIM * 2) + srcx;
    }

    const char* actc = (const char*)act;
    const char* wdc = (const char*)wdT;

    f4 acc[4][8];
#pragma unroll
    for (int mi = 0; mi < 4; ++mi)
#pragma unroll
        for (int ni = 0; ni < 8; ++ni) acc[mi][ni] = (f4)0.0f;

#define STAGE2(KT, XD, DD) {                                                \
    size_t kby_ = (size_t)(KT) * 128;                                       \
    _Pragma("unroll")                                                       \
    for (int i = 0; i < 4; ++i)                                             \
        gload16(actc + aoff[i] + kby_, (XD) + i * 8192 + w * 1024);         \
    _Pragma("unroll")                                                       \
    for (int i = 0; i < 4; ++i)                                             \
        gload16(wdc + doff[i] + kby_, (DD) + i * 8192 + w * 1024);          \
    }

    STAGE2(0, lds, lds + 65536);
    __syncthreads();

    const int NT = IDIM / BK;   // 16
    for (int kt = 0; kt < NT; ++kt) {
        char* Xc = (kt & 1) ? (lds + 32768) : lds;
        char* Xn = (kt & 1) ? lds : (lds + 32768);
        char* Dc = (kt & 1) ? (lds + 98304) : (lds + 65536);
        char* Dn = (kt & 1) ? (lds + 65536) : (lds + 98304);

        if (kt < NT - 1) STAGE2(kt + 1, Xn, Dn);

#pragma unroll
        for (int ks = 0; ks < 2; ++ks) {
            int kb = ks * 64 + ((l >> 4) << 4);
            bh8 a[4], b[8];
#pragma unroll
            for (int mi = 0; mi < 4; ++mi)
                a[mi] = *(const bh8*)(Xc + swz(wm * 64 + mi * 16 + (l & 15), kb));
#pragma unroll
            for (int ni = 0; ni < 8; ++ni)
                b[ni] = *(const bh8*)(Dc + swz(wn * 128 + ni * 16 + (l & 15), kb));
#pragma unroll
            for (int mi = 0; mi < 4; ++mi)
#pragma unroll
                for (int ni = 0; ni < 8; ++ni)
                    acc[mi][ni] = __builtin_amdgcn_mfma_f32_16x16x32_bf16(a[mi], b[ni], acc[mi][ni], 0, 0, 0);
        }
        __syncthreads();
    }

    // epilogue: scale by routing weight, atomic accumulate
#pragma unroll
    for (int mi = 0; mi < 4; ++mi) {
#pragma unroll
        for (int i = 0; i < 4; ++i) {
            int r = rt * BM + wm * 64 + mi * 16 + ((l >> 4) << 2) + i;
            int tok = row_tok[r];
            if (tok < 0) continue;
            float wgt = row_w[r];
            float* op = out + (size_t)tok * HDIM + nt * 256 + wn * 128 + (l & 15);
#pragma unroll
            for (int ni = 0; ni < 8; ++ni)
                atomicAdd(op + ni * 16, acc[mi][ni][i] * wgt);
        }
    }
#undef STAGE2
}

// ---------------- launch ----------------
// ws layout:
//   [0,512): counts(128) | cursor(128) | offs(132)
//   512:            row_tok  CAP*4
//   512+CAP*4:      row_w    CAP*4
//   +:              act      CAP*IDIM*2     (50.3 MB)
//   +actB:          hs_bf16  T*H*2          (33.6 MB)
//   +hsB:           wgT      E*I*H*2        (134.2 MB)
//   +wTB:           wuT      E*I*H*2        (134.2 MB)   -> need2 = 352.7 MB
//   +wTB:           wdT      E*I*H*2        (134.2 MB)   -> need3 = 486.9 MB

extern "C" void kernel_launch(void* const* d_in, const int* in_sizes, int n_in,
                              void* d_out, int out_size, void* d_ws, size_t ws_size,
                              hipStream_t stream) {
    const float* hs     = (const float*)d_in[0];
    const float* logits = (const float*)d_in[1];
    const float* scale  = (const float*)d_in[2];
    const float* wg     = (const float*)d_in[3];
    const float* wu     = (const float*)d_in[4];
    const float* wd     = (const float*)d_in[5];
    float* out = (float*)d_out;

    char* ws = (char*)d_ws;
    int*   counts  = (int*)ws;
    int*   cursor  = counts + 32;
    int*   offs    = cursor + 32;
    int*   row_tok = (int*)(ws + 512);
    float* row_w   = (float*)(ws + 512 + (size_t)CAP * 4);

    size_t base = 512 + (size_t)CAP * 8;
    size_t actB = (size_t)CAP * IDIM * 2;
    size_t hsB  = (size_t)T_TOK * HDIM * 2;
    size_t wTB  = (size_t)NEXP * IDIM * HDIM * 2;

    unsigned short* act = (unsigned short*)(ws + base);
    unsigned short* hsb = (unsigned short*)(ws + base + actB);
    unsigned short* wgT = (unsigned short*)(ws + base + actB + hsB);
    unsigned short* wuT = (unsigned short*)(ws + base + actB + hsB + wTB);
    unsigned short* wdT = (unsigned short*)(ws + base + actB + hsB + 2 * wTB);

    size_t need3 = base + actB + hsB + 3 * wTB;
    bool full = (ws_size >= need3);

    hipMemsetAsync(counts, 0, 512, stream);
    hipMemsetAsync(row_tok, 0xFF, (size_t)CAP * 4, stream);
    hipMemsetAsync(out, 0, (size_t)out_size * sizeof(float), stream);

    route_count_kernel<<<T_TOK / 256, 256, 0, stream>>>(logits, counts);
    offsets_kernel<<<1, 64, 0, stream>>>(counts, offs);
    route_scatter_kernel<<<T_TOK / 256, 256, 0, stream>>>(logits, scale, offs, cursor, row_tok, row_w);

    if (full) {
        prep_all<<<CVB + 3 * TRB, 256, 0, stream>>>(hs, hsb, wg, wgT, wu, wuT, wd, wdT);
        gemm1q_kernel<<<MAX_RT * 8, 512, 0, stream>>>(hsb, wgT, wuT, offs, row_tok, act);
        gemm2q_kernel<<<MAX_RT * 8, 512, 0, stream>>>(act, wdT, offs, row_tok, row_w, out);
    } else {
        prep_all<<<CVB + 2 * TRB, 256, 0, stream>>>(hs, hsb, wg, wgT, wu, wuT, wd, wdT);
        gemm1q_kernel<<<MAX_RT * 8, 512, 0, stream>>>(hsb, wgT, wuT, offs, row_tok, act);
        transpose_wd_kernel<<<TRB, 256, 0, stream>>>(wd, wgT);   // reuse wgT region
        gemm2q_kernel<<<MAX_RT * 8, 512, 0, stream>>>(act, wgT, offs, row_tok, row_w, out);
    }
}

// Round 10
// 712.099 us; speedup vs baseline: 1.5390x; 1.0155x over previous
//
#include <hip/hip_runtime.h>

#define T_TOK 8192
#define HDIM  2048
#define NEXP  32
#define IDIM  1024

#define BM 256
#define BK 64
#define CAP (T_TOK*2 + NEXP*BM)   // 24576 max padded rows
#define MAX_RT (CAP/BM)           // 96 row tiles max
#define TPM 4096                  // 128x128 transpose tiles per matrix (32 experts x 128)
#define CVB 4096                  // cvt_hs blocks (512 thr x 8 elem)

typedef __attribute__((ext_vector_type(8))) short bh8;   // 8 bf16 (4 VGPR) MFMA A/B frag
typedef __attribute__((ext_vector_type(4))) float f4;    // MFMA C/D frag

// fp32 -> bf16 round-to-nearest-even (bit pattern)
__device__ __forceinline__ unsigned short f2bf(float f) {
    unsigned u = __builtin_bit_cast(unsigned, f);
    u += 0x7FFFu + ((u >> 16) & 1u);
    return (unsigned short)(u >> 16);
}

// XOR swizzle: 128-byte LDS rows, byte ^= (row&7)<<4.  (proven 0-conflict, rounds 1-2)
__device__ __forceinline__ int swz(int row, int kb) {
    return row * 128 + (kb ^ ((row & 7) << 4));
}

// async 16B global->LDS (dest = wave-uniform base, HW adds lane*16; source per-lane)
__device__ __forceinline__ void gload16(const void* g, void* l) {
    __builtin_amdgcn_global_load_lds(
        (const __attribute__((address_space(1))) unsigned int*)g,
        (__attribute__((address_space(3))) unsigned int*)l,
        16, 0, 0);
}

// ---------------- routing ----------------

__device__ __forceinline__ void top2(const float* __restrict__ l,
                                     int& b1, float& v1, int& b2, float& v2) {
    v1 = -1e30f; b1 = 0;
#pragma unroll
    for (int e = 0; e < NEXP; ++e) { float v = l[e]; if (v > v1) { v1 = v; b1 = e; } }
    v2 = -1e30f; b2 = 0;
#pragma unroll
    for (int e = 0; e < NEXP; ++e) { if (e == b1) continue; float v = l[e]; if (v > v2) { v2 = v; b2 = e; } }
}

__global__ void route_count_kernel(const float* __restrict__ logits, int* __restrict__ counts) {
    int t = blockIdx.x * blockDim.x + threadIdx.x;
    if (t >= T_TOK) return;
    int b1, b2; float v1, v2;
    top2(logits + (size_t)t * NEXP, b1, v1, b2, v2);
    atomicAdd(&counts[b1], 1);
    atomicAdd(&counts[b2], 1);
}

__global__ void offsets_kernel(const int* __restrict__ counts, int* __restrict__ offs) {
    if (threadIdx.x == 0) {
        int o = 0;
        for (int e = 0; e < NEXP; ++e) { offs[e] = o; o += (counts[e] + BM - 1) & ~(BM - 1); }
        offs[NEXP] = o;
    }
}

__global__ void route_scatter_kernel(const float* __restrict__ logits,
                                     const float* __restrict__ scale,
                                     const int* __restrict__ offs,
                                     int* __restrict__ cursor,
                                     int* __restrict__ row_tok,
                                     float* __restrict__ row_w) {
    int t = blockIdx.x * blockDim.x + threadIdx.x;
    if (t >= T_TOK) return;
    int b1, b2; float v1, v2;
    top2(logits + (size_t)t * NEXP, b1, v1, b2, v2);
    float e2 = expf(v2 - v1);
    float inv = 1.0f / (1.0f + e2);
    float w1 = scale[b1] * inv;
    float w2 = scale[b2] * e2 * inv;
    int p1 = offs[b1] + atomicAdd(&cursor[b1], 1);
    row_tok[p1] = t; row_w[p1] = w1;
    int p2 = offs[b2] + atomicAdd(&cursor[b2], 1);
    row_tok[p2] = t; row_w[p2] = w2;
}

// ---------------- prep v3: gload16-staged 128x128 transpose+convert ----------------

// [E][K][N] fp32 -> [E][N][K] bf16, one 128x128 tile per 512-thread block.
// Phase 1: 8x gload16/thread, linear LDS [128][128] fp32, bank-swizzle applied by
// pre-swizzling the global source chunk (chunk ^= ((k>>3)&3)<<1 -- same involution
// used on the read side, rule 21).
// Phase 2: thread (n = t>>2, kc = 8*(t&3)+32p): 8 ds_read_b32 (2-way banks = free)
// -> bh8 -> one b128 store; 4 lanes/row = 64B-aligned full-line write segments.
__device__ __forceinline__ void transpose_cvt_dev(const float* __restrict__ in,
                                                  unsigned short* __restrict__ out,
                                                  int K, int N, int bid,
                                                  char* __restrict__ ldsb) {
    int e = bid >> 7;            // 128 tiles per expert for both shapes
    int tile = bid & 127;
    int tN = N >> 7;
    int k0 = (tile / tN) << 7;
    int n0 = (tile % tN) << 7;
    const char* src = (const char*)(in + (size_t)e * K * N + (size_t)k0 * N + n0);
    char* dst = (char*)(out + (size_t)e * K * N + (size_t)n0 * K + k0);

    int t = threadIdx.x;
    // phase 1: async DMA, coalesced full 512B source rows (order permuted by swizzle)
#pragma unroll
    for (int i = 0; i < 8; ++i) {
        int c = i * 512 + t;                       // dest chunk 0..4095
        int k = c >> 5;                            // 0..127
        int cc = (c & 31) ^ (((k >> 3) & 3) << 1); // pre-swizzled source chunk
        gload16(src + (size_t)k * N * 4 + cc * 16, ldsb + i * 8192 + (t >> 6) * 1024);
    }
    __syncthreads();
    // phase 2: column gather (swizzled), 64B-coalesced dst row segments
    int n = t >> 2;              // 0..127
    int lk = (t & 3) * 8;
#pragma unroll
    for (int p = 0; p < 4; ++p) {
        int kc = lk + 32 * p;
        bh8 v;
#pragma unroll
        for (int j = 0; j < 8; ++j) {
            int k = kc + j;
            int ch = (k * 32 + (n >> 2)) ^ (((k >> 3) & 3) << 1);
            float f = *(const float*)(ldsb + ch * 16 + (n & 3) * 4);
            v[j] = (short)f2bf(f);
        }
        *(bh8*)(dst + (size_t)n * K * 2 + kc * 2) = v;
    }
}

// Fused: cvt_hs | wg transpose | wu transpose | (optional) wd transpose.
// Grid = CVB + 2*TPM (fallback) or CVB + 3*TPM (full). 512 threads.
__global__ void prep_all(const float* __restrict__ hs, unsigned short* __restrict__ hsb,
                         const float* __restrict__ wg, unsigned short* __restrict__ wgT,
                         const float* __restrict__ wu, unsigned short* __restrict__ wuT,
                         const float* __restrict__ wd, unsigned short* __restrict__ wdT) {
    __shared__ float tl[16384];   // 64 KB
    int b = blockIdx.x;
    if (b < CVB) {
        size_t i = ((size_t)b * 512 + threadIdx.x) * 8;
        float4 a = *(const float4*)(hs + i);
        float4 c = *(const float4*)(hs + i + 4);
        bh8 v;
        v[0] = (short)f2bf(a.x); v[1] = (short)f2bf(a.y);
        v[2] = (short)f2bf(a.z); v[3] = (short)f2bf(a.w);
        v[4] = (short)f2bf(c.x); v[5] = (short)f2bf(c.y);
        v[6] = (short)f2bf(c.z); v[7] = (short)f2bf(c.w);
        *(bh8*)(hsb + i) = v;
        return;
    }
    b -= CVB;
    int mat = b >> 12;
    int bid = b & 4095;
    if (mat == 0)      transpose_cvt_dev(wg, wgT, HDIM, IDIM, bid, (char*)tl);
    else if (mat == 1) transpose_cvt_dev(wu, wuT, HDIM, IDIM, bid, (char*)tl);
    else               transpose_cvt_dev(wd, wdT, IDIM, HDIM, bid, (char*)tl);
}

// standalone wd transpose (serial fallback path), 512 threads x TPM blocks
__global__ void transpose_wd_kernel(const float* __restrict__ wd, unsigned short* __restrict__ wdT) {
    __shared__ float tl[16384];
    transpose_cvt_dev(wd, wdT, IDIM, HDIM, blockIdx.x, (char*)tl);
}

// ============ GEMM1 (T3-minimum): act = gelu(X@Wg) * (X@Wu) ============
// 512 threads, BM=256 x BN=128 (G and U each). Waves 4m x 2n, wave = 64r x 64c dual.
// ALL operands gload16 double-buffered; STAGE(t+1) issued BEFORE compute(t);
// ONE barrier per K-tile (vmcnt drain lands after a full compute phase).
__launch_bounds__(512, 2)
__global__ void gemm1q_kernel(const unsigned short* __restrict__ hsb,
                              const unsigned short* __restrict__ wgT,
                              const unsigned short* __restrict__ wuT,
                              const int* __restrict__ offs,
                              const int* __restrict__ row_tok,
                              unsigned short* __restrict__ act) {
    __shared__ char lds[131072];
    // X0 @0 (32K) | X1 @32768 | G0 @65536 (16K) | G1 @81920 | U0 @98304 | U1 @114688

    int gid = blockIdx.x;
    int rt = gid >> 3;
    int nt = gid & 7;          // IDIM/128
    if (rt * BM >= offs[NEXP]) return;
    int e = 0;
    while (offs[e + 1] <= rt * BM) e++;

    int tid = threadIdx.x, l = tid & 63, w = tid >> 6;
    int wm = w >> 1, wn = w & 1;

    // pre-swizzled per-lane source chunk within a 128B row
    unsigned srcx = ((l & 7) * 16) ^ ((l >> 3) << 4);

    size_t xoff[4];
#pragma unroll
    for (int i = 0; i < 4; ++i) {
        int tok = row_tok[rt * BM + i * 64 + w * 8 + (l >> 3)];
        if (tok < 0) tok = 0;
        xoff[i] = (size_t)tok * (HDIM * 2) + srcx;
    }
    size_t goff[2];
#pragma unroll
    for (int i = 0; i < 2; ++i) {
        int r = i * 64 + w * 8 + (l >> 3);   // 0..127
        goff[i] = ((size_t)e * IDIM + nt * 128 + r) * (HDIM * 2) + srcx;
    }

    const char* hsc = (const char*)hsb;
    const char* wgc = (const char*)wgT;
    const char* wuc = (const char*)wuT;

    f4 accG[4][4], accU[4][4];
#pragma unroll
    for (int mi = 0; mi < 4; ++mi)
#pragma unroll
        for (int ni = 0; ni < 4; ++ni) { accG[mi][ni] = (f4)0.0f; accU[mi][ni] = (f4)0.0f; }

#define STAGE1(KT, XD, GD, UD) {                                            \
    size_t kby_ = (size_t)(KT) * 128;                                       \
    _Pragma("unroll")                                                       \
    for (int i = 0; i < 4; ++i)                                             \
        gload16(hsc + xoff[i] + kby_, (XD) + i * 8192 + w * 1024);          \
    _Pragma("unroll")                                                       \
    for (int i = 0; i < 2; ++i)                                             \
        gload16(wgc + goff[i] + kby_, (GD) + i * 8192 + w * 1024);          \
    _Pragma("unroll")                                                       \
    for (int i = 0; i < 2; ++i)                                             \
        gload16(wuc + goff[i] + kby_, (UD) + i * 8192 + w * 1024);          \
    }

    STAGE1(0, lds, lds + 65536, lds + 98304);
    __syncthreads();

    const int NT = HDIM / BK;   // 32
    for (int kt = 0; kt < NT; ++kt) {
        char* Xc = (kt & 1) ? (lds + 32768) : lds;
        char* Xn = (kt & 1) ? lds : (lds + 32768);
        char* Gc = (kt & 1) ? (lds + 81920) : (lds + 65536);
        char* Gn = (kt & 1) ? (lds + 65536) : (lds + 81920);
        char* Uc = (kt & 1) ? (lds + 114688) : (lds + 98304);
        char* Un = (kt & 1) ? (lds + 98304) : (lds + 114688);

        if (kt < NT - 1) STAGE1(kt + 1, Xn, Gn, Un);   // issued before compute

#pragma unroll
        for (int ks = 0; ks < 2; ++ks) {
            int kb = ks * 64 + ((l >> 4) << 4);
            bh8 a[4], g[4], u[4];
#pragma unroll
            for (int mi = 0; mi < 4; ++mi)
                a[mi] = *(const bh8*)(Xc + swz(wm * 64 + mi * 16 + (l & 15), kb));
#pragma unroll
            for (int ni = 0; ni < 4; ++ni) {
                int nr = wn * 64 + ni * 16 + (l & 15);
                g[ni] = *(const bh8*)(Gc + swz(nr, kb));
                u[ni] = *(const bh8*)(Uc + swz(nr, kb));
            }
#pragma unroll
            for (int mi = 0; mi < 4; ++mi)
#pragma unroll
                for (int ni = 0; ni < 4; ++ni) {
                    accG[mi][ni] = __builtin_amdgcn_mfma_f32_16x16x32_bf16(a[mi], g[ni], accG[mi][ni], 0, 0, 0);
                    accU[mi][ni] = __builtin_amdgcn_mfma_f32_16x16x32_bf16(a[mi], u[ni], accU[mi][ni], 0, 0, 0);
                }
        }
        __syncthreads();   // drains STAGE(kt+1) vmem (issued a full compute ago)
    }

    // epilogue: gelu(g)*u -> bf16 act, pre-swizzled byte layout
    char* actc = (char*)act;
#pragma unroll
    for (int mi = 0; mi < 4; ++mi) {
#pragma unroll
        for (int i = 0; i < 4; ++i) {
            int r = rt * BM + wm * 64 + mi * 16 + ((l >> 4) << 2) + i;
            size_t rowbase = (size_t)r * (IDIM * 2);
            int rs = (r & 7) << 4;
#pragma unroll
            for (int ni = 0; ni < 4; ++ni) {
                int col = nt * 128 + wn * 64 + ni * 16 + (l & 15);
                float gv = accG[mi][ni][i], uv = accU[mi][ni][i];
                float gl = 0.5f * gv * (1.0f + erff(gv * 0.70710678118654752f));
                *(unsigned short*)(actc + rowbase + ((col * 2) ^ rs)) = f2bf(gl * uv);
            }
        }
    }
#undef STAGE1
}

// ============ GEMM2 (T3-minimum): out[tok] += w * (act @ WdT^T) ============
// 512 threads, BM=256 x BN=256. Waves 4m x 2n, wave = 64r x 128c.
__launch_bounds__(512, 2)
__global__ void gemm2q_kernel(const unsigned short* __restrict__ act,
                              const unsigned short* __restrict__ wdT,
                              const int* __restrict__ offs,
                              const int* __restrict__ row_tok,
                              const float* __restrict__ row_w,
                              float* __restrict__ out) {
    __shared__ char lds[131072];
    // X0 @0 (32K) | X1 @32768 | D0 @65536 (32K) | D1 @98304

    int gid = blockIdx.x;
    int rt = gid >> 3;
    int nt = gid & 7;          // HDIM/256
    if (rt * BM >= offs[NEXP]) return;
    int e = 0;
    while (offs[e + 1] <= rt * BM) e++;

    int tid = threadIdx.x, l = tid & 63, w = tid >> 6;
    int wm = w >> 1, wn = w & 1;

    unsigned srcx = ((l & 7) * 16) ^ ((l >> 3) << 4);

    size_t aoff[4];
#pragma unroll
    for (int i = 0; i < 4; ++i)
        aoff[i] = (size_t)(rt * BM + i * 64 + w * 8 + (l >> 3)) * (IDIM * 2) + (l & 7) * 16;
    size_t doff[4];
#pragma unroll
    for (int i = 0; i < 4; ++i) {
        int r = i * 64 + w * 8 + (l >> 3);   // 0..255
        doff[i] = ((size_t)e * HDIM + nt * 256 + r) * (IDIM * 2) + srcx;
    }

    const char* actc = (const char*)act;
    const char* wdc = (const char*)wdT;

    f4 acc[4][8];
#pragma unroll
    for (int mi = 0; mi < 4; ++mi)
#pragma unroll
        for (int ni = 0; ni < 8; ++ni) acc[mi][ni] = (f4)0.0f;

#define STAGE2(KT, XD, DD) {                                                \
    size_t kby_ = (size_t)(KT) * 128;                                       \
    _Pragma("unroll")                                                       \
    for (int i = 0; i < 4; ++i)                                             \
        gload16(actc + aoff[i] + kby_, (XD) + i * 8192 + w * 1024);         \
    _Pragma("unroll")                                                       \
    for (int i = 0; i < 4; ++i)                                             \
        gload16(wdc + doff[i] + kby_, (DD) + i * 8192 + w * 1024);          \
    }

    STAGE2(0, lds, lds + 65536);
    __syncthreads();

    const int NT = IDIM / BK;   // 16
    for (int kt = 0; kt < NT; ++kt) {
        char* Xc = (kt & 1) ? (lds + 32768) : lds;
        char* Xn = (kt & 1) ? lds : (lds + 32768);
        char* Dc = (kt & 1) ? (lds + 98304) : (lds + 65536);
        char* Dn = (kt & 1) ? (lds + 65536) : (lds + 98304);

        if (kt < NT - 1) STAGE2(kt + 1, Xn, Dn);

#pragma unroll
        for (int ks = 0; ks < 2; ++ks) {
            int kb = ks * 64 + ((l >> 4) << 4);
            bh8 a[4], b[8];
#pragma unroll
            for (int mi = 0; mi < 4; ++mi)
                a[mi] = *(const bh8*)(Xc + swz(wm * 64 + mi * 16 + (l & 15), kb));
#pragma unroll
            for (int ni = 0; ni < 8; ++ni)
                b[ni] = *(const bh8*)(Dc + swz(wn * 128 + ni * 16 + (l & 15), kb));
#pragma unroll
            for (int mi = 0; mi < 4; ++mi)
#pragma unroll
                for (int ni = 0; ni < 8; ++ni)
                    acc[mi][ni] = __builtin_amdgcn_mfma_f32_16x16x32_bf16(a[mi], b[ni], acc[mi][ni], 0, 0, 0);
        }
        __syncthreads();
    }

    // epilogue: scale by routing weight, atomic accumulate
#pragma unroll
    for (int mi = 0; mi < 4; ++mi) {
#pragma unroll
        for (int i = 0; i < 4; ++i) {
            int r = rt * BM + wm * 64 + mi * 16 + ((l >> 4) << 2) + i;
            int tok = row_tok[r];
            if (tok < 0) continue;
            float wgt = row_w[r];
            float* op = out + (size_t)tok * HDIM + nt * 256 + wn * 128 + (l & 15);
#pragma unroll
            for (int ni = 0; ni < 8; ++ni)
                atomicAdd(op + ni * 16, acc[mi][ni][i] * wgt);
        }
    }
#undef STAGE2
}

// ---------------- launch ----------------
// ws layout:
//   [0,512): counts(128) | cursor(128) | offs(132)
//   512:            row_tok  CAP*4
//   512+CAP*4:      row_w    CAP*4
//   +:              act      CAP*IDIM*2     (50.3 MB)
//   +actB:          hs_bf16  T*H*2          (33.6 MB)
//   +hsB:           wgT      E*I*H*2        (134.2 MB)
//   +wTB:           wuT      E*I*H*2        (134.2 MB)   -> need2 = 352.7 MB
//   +wTB:           wdT      E*I*H*2        (134.2 MB)   -> need3 = 486.9 MB

extern "C" void kernel_launch(void* const* d_in, const int* in_sizes, int n_in,
                              void* d_out, int out_size, void* d_ws, size_t ws_size,
                              hipStream_t stream) {
    const float* hs     = (const float*)d_in[0];
    const float* logits = (const float*)d_in[1];
    const float* scale  = (const float*)d_in[2];
    const float* wg     = (const float*)d_in[3];
    const float* wu     = (const float*)d_in[4];
    const float* wd     = (const float*)d_in[5];
    float* out = (float*)d_out;

    char* ws = (char*)d_ws;
    int*   counts  = (int*)ws;
    int*   cursor  = counts + 32;
    int*   offs    = cursor + 32;
    int*   row_tok = (int*)(ws + 512);
    float* row_w   = (float*)(ws + 512 + (size_t)CAP * 4);

    size_t base = 512 + (size_t)CAP * 8;
    size_t actB = (size_t)CAP * IDIM * 2;
    size_t hsB  = (size_t)T_TOK * HDIM * 2;
    size_t wTB  = (size_t)NEXP * IDIM * HDIM * 2;

    unsigned short* act = (unsigned short*)(ws + base);
    unsigned short* hsb = (unsigned short*)(ws + base + actB);
    unsigned short* wgT = (unsigned short*)(ws + base + actB + hsB);
    unsigned short* wuT = (unsigned short*)(ws + base + actB + hsB + wTB);
    unsigned short* wdT = (unsigned short*)(ws + base + actB + hsB + 2 * wTB);

    size_t need3 = base + actB + hsB + 3 * wTB;
    bool full = (ws_size >= need3);

    hipMemsetAsync(counts, 0, 512, stream);
    hipMemsetAsync(row_tok, 0xFF, (size_t)CAP * 4, stream);
    hipMemsetAsync(out, 0, (size_t)out_size * sizeof(float), stream);

    route_count_kernel<<<T_TOK / 256, 256, 0, stream>>>(logits, counts);
    offsets_kernel<<<1, 64, 0, stream>>>(counts, offs);
    route_scatter_kernel<<<T_TOK / 256, 256, 0, stream>>>(logits, scale, offs, cursor, row_tok, row_w);

    if (full) {
        prep_all<<<CVB + 3 * TPM, 512, 0, stream>>>(hs, hsb, wg, wgT, wu, wuT, wd, wdT);
        gemm1q_kernel<<<MAX_RT * 8, 512, 0, stream>>>(hsb, wgT, wuT, offs, row_tok, act);
        gemm2q_kernel<<<MAX_RT * 8, 512, 0, stream>>>(act, wdT, offs, row_tok, row_w, out);
    } else {
        prep_all<<<CVB + 2 * TPM, 512, 0, stream>>>(hs, hsb, wg, wgT, wu, wuT, wd, wdT);
        gemm1q_kernel<<<MAX_RT * 8, 512, 0, stream>>>(hsb, wgT, wuT, offs, row_tok, act);
        transpose_wd_kernel<<<TPM, 512, 0, stream>>>(wd, wgT);   // reuse wgT region
        gemm2q_kernel<<<MAX_RT * 8, 512, 0, stream>>>(act, wgT, offs, row_tok, row_w, out);
    }
}